// Round 9
// baseline (277.579 us; speedup 1.0000x reference)
//
#include <hip/hip_runtime.h>
#include <hip/hip_bf16.h>

// CQAttention: B=16, Lc=1024, Lq=512, d=512.  f32 I/O, bf16 MFMA GEMMs, f32 acc.
// Round 17: (1) P-core v3 "pair-phase" for the four pure GEMMs — 4 single-step
// buffers (48 KiB, 3 blocks/CU), ONE {vmcnt(0); barrier; stage pair q+1;
// compute 2 steps} phase per 64-K: 16 MFMA per barrier (2x R8) at the same
// ~300cy load-flight (vmcnt(0) covers only the needed pair since nothing else
// is in flight).  Stage targets pair q-1's slots, safe by the top barrier.
// (2) T5: s_setprio(1/0) around O-core's MFMA cluster (phase-diverse counted
// pipeline = the regime where setprio pays).  (3) A/Bm epilogues read bf16 Cbf
// instead of f32 C in the big-ws path (-32 MiB HBM traffic).

#define NB 16
#define LC 1024
#define LQ 512
#define DM 512
#define D4 2048
#define NEGINF (-1e30f)

typedef __bf16 v8bf __attribute__((ext_vector_type(8)));
typedef __bf16 v4bf __attribute__((ext_vector_type(4)));
typedef float  v4f  __attribute__((ext_vector_type(4)));

#define MFMA16 __builtin_amdgcn_mfma_f32_16x16x32_bf16

// direct global->LDS async copy, 16B per lane; LDS dest is wave-uniform base.
#define GLOAD16(gp, lp) __builtin_amdgcn_global_load_lds( \
    (const __attribute__((address_space(1))) void*)(gp), \
    (__attribute__((address_space(3))) void*)(lp), 16, 0, 0)

// XCD-aware remap.
__device__ __forceinline__ void xcd_remap(int& bx, int& by, int& bz) {
  const int gx = gridDim.x, gy = gridDim.y, gz = gridDim.z;
  int flat = bx + gx * (by + gy * bz);
  int per = (gx * gy * gz) >> 3;
  int nw = (flat & 7) * per + (flat >> 3);
  bx = nw % gx;
  int r = nw / gx;
  by = r % gy;
  bz = r / gy;
}

// ===== CORE P v3 (pure GEMMs): tile 128x64, BK=32, 4-buf pair-phase =====
// LDS row = 32 elems (64 B) = 4 chunks of 16 B; chunk c of row r at slot
// c ^ (r&3) ^ ((r>>2)&3) (validated swizzle pair).  Phase q: wait pair q
// (vmcnt(0): only its 6 loads in flight), barrier (all waves done reading
// pair q-1), stage pair q+1 into pair q-1's slots, compute pair q (16 MFMA).
#define P_PROLOG \
  __shared__ __bf16 Al[4][128 * 32], Bl[4][64 * 32]; \
  int bx = blockIdx.x, by = blockIdx.y, bz = blockIdx.z; \
  xcd_remap(bx, by, bz); \
  const int b = bz, i0 = by * 128, n0 = bx * 64; \
  const int t = threadIdx.x, lane = t & 63, wave = t >> 6; \
  const int wm = wave >> 1, wn = wave & 1, quad = lane >> 4, col = lane & 15; \
  const int srA = wave * 32 + (lane >> 2); \
  const int srB = wave * 16 + (lane >> 2); \
  const int swz = (((lane & 3) ^ ((lane >> 2) & 3) ^ ((lane >> 4) & 3)) * 8); \
  const int rdx = ((quad ^ (col & 3) ^ ((col >> 2) & 3)) * 8); \
  v4f acc[4][2]; \
  _Pragma("unroll") for (int x = 0; x < 4; ++x) \
  _Pragma("unroll") for (int y = 0; y < 2; ++y) \
  _Pragma("unroll") for (int r = 0; r < 4; ++r) acc[x][y][r] = 0.f;

// stage one BK=32 step into slot s (3 gload16 per thread).
#define P_STAGE1(s, Aptr, Bptr, LDGA, LDGB, k0) \
  do { \
    GLOAD16((Aptr) + (k0),                       &Al[s][(wave * 32) * 32]); \
    GLOAD16((Aptr) + (size_t)16 * (LDGA) + (k0), &Al[s][(wave * 32 + 16) * 32]); \
    GLOAD16((Bptr) + (k0),                       &Bl[s][(wave * 16) * 32]); \
  } while (0)

// one BK=32 step: 6 ds_read_b128 + 8 MFMA per wave.
#define P_COMPUTE(buf) \
  do { \
    v8bf af_[4], bf_[2]; \
    _Pragma("unroll") for (int x = 0; x < 4; ++x) \
      af_[x] = *(const v8bf*)&Al[buf][(wm * 64 + x * 16 + col) * 32 + rdx]; \
    _Pragma("unroll") for (int y = 0; y < 2; ++y) \
      bf_[y] = *(const v8bf*)&Bl[buf][(wn * 32 + y * 16 + col) * 32 + rdx]; \
    _Pragma("unroll") for (int x = 0; x < 4; ++x) \
    _Pragma("unroll") for (int y = 0; y < 2; ++y) \
      acc[x][y] = MFMA16(af_[x], bf_[y], acc[x][y], 0, 0, 0); \
  } while (0)

// KEXT multiple of 64 (>= 128).
#define P_KLOOP(Arow, Brow, LDGA, LDGB, KEXT) \
  { P_STAGE1(0, Arow, Brow, LDGA, LDGB, 0); \
    P_STAGE1(1, Arow, Brow, LDGA, LDGB, 32); \
    const int np_ = (KEXT) / 64; \
    for (int q = 0; q < np_; ++q) { \
      asm volatile("s_waitcnt vmcnt(0)" ::: "memory"); \
      __builtin_amdgcn_s_barrier(); \
      const int s0_ = (2 * q) & 3, s1_ = s0_ + 1; \
      if (q + 1 < np_) { \
        const int t0_ = (2 * q + 2) & 3, t1_ = t0_ + 1; \
        P_STAGE1(t0_, Arow, Brow, LDGA, LDGB, (q + 1) * 64); \
        P_STAGE1(t1_, Arow, Brow, LDGA, LDGB, (q + 1) * 64 + 32); \
      } \
      P_COMPUTE(s0_); \
      P_COMPUTE(s1_); \
    } }

// ====== CORE O (k_mfma_out): tile 128x128, BK=32, 3-buf, counted vmcnt ======
#define O_PROLOG \
  __shared__ __bf16 Al[3][128 * 32], Bl[3][128 * 32]; \
  int bx = blockIdx.x, by = blockIdx.y, bz = blockIdx.z; \
  xcd_remap(bx, by, bz); \
  const int b = bz, i0 = by * 128, n0 = bx * 128; \
  const int t = threadIdx.x, lane = t & 63, wave = t >> 6; \
  const int wm = wave >> 1, wn = wave & 1, quad = lane >> 4, col = lane & 15; \
  const int sr32 = wave * 32 + (lane >> 2); \
  const int swz = (((lane & 3) ^ ((lane >> 2) & 3) ^ ((lane >> 4) & 3)) * 8); \
  const int rdx = ((quad ^ (col & 3) ^ ((col >> 2) & 3)) * 8); \
  v4f acc[4][4]; \
  _Pragma("unroll") for (int x = 0; x < 4; ++x) \
  _Pragma("unroll") for (int y = 0; y < 4; ++y) \
  _Pragma("unroll") for (int r = 0; r < 4; ++r) acc[x][y][r] = 0.f;

#define O_STAGE(buf, Aptr, Bptr, LDGA, LDGB, k0) \
  do { \
    GLOAD16((Aptr) + (k0),                       &Al[buf][(wave * 32) * 32]); \
    GLOAD16((Aptr) + (size_t)16 * (LDGA) + (k0), &Al[buf][(wave * 32 + 16) * 32]); \
    GLOAD16((Bptr) + (k0),                       &Bl[buf][(wave * 32) * 32]); \
    GLOAD16((Bptr) + (size_t)16 * (LDGB) + (k0), &Bl[buf][(wave * 32 + 16) * 32]); \
  } while (0)

// T5: setprio(1) around the MFMA cluster (phase-diverse pipeline regime).
#define O_COMPUTE(buf) \
  do { \
    v8bf af_[4], bf_[4]; \
    _Pragma("unroll") for (int x = 0; x < 4; ++x) \
      af_[x] = *(const v8bf*)&Al[buf][(wm * 64 + x * 16 + col) * 32 + rdx]; \
    _Pragma("unroll") for (int y = 0; y < 4; ++y) \
      bf_[y] = *(const v8bf*)&Bl[buf][(wn * 64 + y * 16 + col) * 32 + rdx]; \
    __builtin_amdgcn_s_setprio(1); \
    _Pragma("unroll") for (int x = 0; x < 4; ++x) \
    _Pragma("unroll") for (int y = 0; y < 4; ++y) \
      acc[x][y] = MFMA16(af_[x], bf_[y], acc[x][y], 0, 0, 0); \
    __builtin_amdgcn_s_setprio(0); \
  } while (0)

#define O_SYNC4() \
  do { asm volatile("s_waitcnt vmcnt(4)" ::: "memory"); \
       __builtin_amdgcn_s_barrier(); } while (0)
#define O_SYNC0() \
  do { asm volatile("s_waitcnt vmcnt(0)" ::: "memory"); \
       __builtin_amdgcn_s_barrier(); } while (0)

#define O_ROT() do { cur_ = (cur_ == 2) ? 0 : cur_ + 1; \
                     nx2_ = (nx2_ == 2) ? 0 : nx2_ + 1; } while (0)

// -------- K1: cw1[b,i] = C.w1, qw2[b,j] = Q.w2; also emits Cbf = bf16(C)
// -------- and Qw3 = bf16(Q*w3) for the pure-bf16 k_mfma_S. ----
__global__ void k_rowdots(const float* __restrict__ C, const float* __restrict__ Q,
                          const float* __restrict__ w,
                          float* __restrict__ cw1, float* __restrict__ qw2,
                          __bf16* __restrict__ Cbf, __bf16* __restrict__ Qw3) {
  const int wid = threadIdx.x >> 6, lane = threadIdx.x & 63;
  const int row = blockIdx.x * 4 + wid;
  const bool isC = row < NB * LC;
  const int lr = isC ? row : row - NB * LC;
  const float* src = (isC ? C : Q) + (size_t)lr * DM;
  const float* wv  = isC ? w : (w + DM);
  const float* w3  = w + 2 * DM;
  __bf16* dst = (isC ? Cbf : Qw3) + (size_t)lr * DM;
  float v = 0.f;
#pragma unroll
  for (int s = 0; s < 2; ++s) {
    const int k = lane * 4 + s * 256;
    float4 f = *(const float4*)(src + k);
    float4 g = *(const float4*)(wv + k);
    v += f.x * g.x + f.y * g.y + f.z * g.z + f.w * g.w;
    v4bf h;
    if (isC) {
      h[0] = (__bf16)f.x; h[1] = (__bf16)f.y; h[2] = (__bf16)f.z; h[3] = (__bf16)f.w;
    } else {
      float4 s3 = *(const float4*)(w3 + k);
      h[0] = (__bf16)(f.x * s3.x); h[1] = (__bf16)(f.y * s3.y);
      h[2] = (__bf16)(f.z * s3.z); h[3] = (__bf16)(f.w * s3.w);
    }
    *(v4bf*)(dst + k) = h;
  }
#pragma unroll
  for (int off = 32; off; off >>= 1) v += __shfl_down(v, off, 64);
  if (lane == 0) {
    if (isC) cw1[row] = v;
    else     qw2[lr] = v;
  }
}

// ------- transpose cores: in[R][Cd] -> bf16 outT[Cd][R], one 64x64 tile ----
__device__ __forceinline__ void transpose_tile_f32(const float* __restrict__ in,
                                                   __bf16* __restrict__ outT,
                                                   int R, int Cd, int tbx, int tby, int tb) {
  __shared__ __bf16 tile[64][66];
  const int r0 = tby * 64, c0 = tbx * 64;
  const int tr = threadIdx.x >> 6, tc = threadIdx.x & 63;
  const float* inb = in + (size_t)tb * R * Cd;
  __bf16* outb = outT + (size_t)tb * Cd * R;
  for (int r = tr; r < 64; r += 4)
    tile[r][tc] = (__bf16)inb[(size_t)(r0 + r) * Cd + c0 + tc];
  __syncthreads();
  for (int c = tr; c < 64; c += 4)
    outb[(size_t)(c0 + c) * R + r0 + tc] = tile[tc][c];
}

__device__ __forceinline__ void transpose_tile_bf(const __bf16* __restrict__ in,
                                                  __bf16* __restrict__ outT,
                                                  int R, int Cd, int tbx, int tby, int tb) {
  __shared__ __bf16 tile[64][66];
  const int r0 = tby * 64, c0 = tbx * 64;
  const int tr = threadIdx.x >> 6, tc = threadIdx.x & 63;
  const __bf16* inb = in + (size_t)tb * R * Cd;
  __bf16* outb = outT + (size_t)tb * Cd * R;
  for (int r = tr; r < 64; r += 4)
    tile[r][tc] = inb[(size_t)(r0 + r) * Cd + c0 + tc];
  __syncthreads();
  for (int c = tr; c < 64; c += 4)
    outb[(size_t)(c0 + c) * R + r0 + tc] = tile[tc][c];
}

// ------- merged prep: transpose C (2048 blks, from Cbf when available) +
// ------- transpose Q (1024 blks) [+ OW cvt (1024 blks) in big-ws path] ----
__global__ void k_prep(const float* __restrict__ C, const __bf16* __restrict__ Cbf,
                       const float* __restrict__ Q, const float* __restrict__ OW,
                       __bf16* __restrict__ CT, __bf16* __restrict__ QT,
                       __bf16* __restrict__ OWb, int use_cbf) {
  const int id = blockIdx.x;
  if (id < 2048) {                      // C^T: (8, 16, 16)
    if (use_cbf) transpose_tile_bf(Cbf, CT, LC, DM, id & 7, (id >> 3) & 15, id >> 7);
    else         transpose_tile_f32(C,  CT, LC, DM, id & 7, (id >> 3) & 15, id >> 7);
  } else if (id < 3072) {               // Q^T: (8, 8, 16)
    const int id2 = id - 2048;
    transpose_tile_f32(Q, QT, LQ, DM, id2 & 7, (id2 >> 3) & 7, id2 >> 6);
  } else {                              // OW cvt: 1024 blocks x 1024 elems
    const size_t i = ((size_t)(id - 3072) * 256 + threadIdx.x) * 4;
    float4 f = *(const float4*)(OW + i);
    v4bf h; h[0] = (__bf16)f.x; h[1] = (__bf16)f.y; h[2] = (__bf16)f.z; h[3] = (__bf16)f.w;
    *(v4bf*)(OWb + i) = h;
  }
}

// ------- fallback late cvt: Cbf3 = bf16(C) and OWbf = bf16(out_w) -------
__global__ void k_cvt2b(const float* __restrict__ Cf, const float* __restrict__ OW,
                        __bf16* __restrict__ Cb3, __bf16* __restrict__ OWb) {
  const size_t NC = (size_t)NB * LC * DM;
  size_t i = ((size_t)blockIdx.x * 256 + threadIdx.x) * 4;
  if (i < NC) {
    float4 f = *(const float4*)(Cf + i);
    v4bf h; h[0] = (__bf16)f.x; h[1] = (__bf16)f.y; h[2] = (__bf16)f.z; h[3] = (__bf16)f.w;
    *(v4bf*)(Cb3 + i) = h;
  } else {
    size_t j = i - NC;
    float4 f = *(const float4*)(OW + j);
    v4bf h; h[0] = (__bf16)f.x; h[1] = (__bf16)f.y; h[2] = (__bf16)f.z; h[3] = (__bf16)f.w;
    *(v4bf*)(OWb + j) = h;
  }
}

// ---------------- G1: S = cw1 + qw2 + Cbf @ Qw3^T ----------------
__global__ __launch_bounds__(256) void k_mfma_S(
    const __bf16* __restrict__ Cbf, const __bf16* __restrict__ Qw3,
    const float* __restrict__ cw1, const float* __restrict__ qw2,
    float* __restrict__ S) {
  P_PROLOG
  const __bf16* Arow = Cbf + (size_t)b * LC * DM + (size_t)(i0 + srA) * DM + swz;
  const __bf16* Brow = Qw3 + (size_t)b * LQ * DM + (size_t)(n0 + srB) * DM + swz;
  P_KLOOP(Arow, Brow, DM, DM, DM)
  float* Sb = S + (size_t)b * LC * LQ;
#pragma unroll
  for (int x = 0; x < 4; ++x) {
    const int mB = i0 + wm * 64 + x * 16 + quad * 4;
    float cv[4];
#pragma unroll
    for (int r = 0; r < 4; ++r) cv[r] = cw1[b * LC + mB + r];
#pragma unroll
    for (int y = 0; y < 2; ++y) {
      const int j = n0 + wn * 32 + y * 16 + col;
      const float qv = qw2[b * LQ + j];
#pragma unroll
      for (int r = 0; r < 4; ++r)
        Sb[(size_t)(mB + r) * LQ + j] = acc[x][y][r] + cv[r] + qv;
    }
  }
}

// ---- fused: row softmax (qmask) -> S1  AND  per-64i-chunk column stats ----
__global__ __launch_bounds__(1024) void k_softstat(
    const float* __restrict__ S, const float* __restrict__ qmask,
    const float* __restrict__ cmask, __bf16* __restrict__ S1,
    float2* __restrict__ pstat) {
  __shared__ float2 cst[16][LQ];
  const int b = blockIdx.y, ic = blockIdx.x;
  const int tid = threadIdx.x, wv = tid >> 6, lane = tid & 63;
  const float* qm  = qmask + b * LQ;
  const float* cm  = cmask + b * LC + ic * 64;
  const float* Sb  = S  + ((size_t)b * LC + ic * 64) * LQ;
  __bf16*      S1b = S1 + ((size_t)b * LC + ic * 64) * LQ;
  float colm[8], cols[8];
#pragma unroll
  for (int tt = 0; tt < 8; ++tt) { colm[tt] = -3e38f; cols[tt] = 0.f; }
  for (int it = 0; it < 4; ++it) {
    const int r = wv * 4 + it;
    const float cmv = cm[r];
    const float* Srow = Sb + (size_t)r * LQ;
    float sv[8], l1[8];
    float m = -3e38f;
#pragma unroll
    for (int tt = 0; tt < 8; ++tt) {
      int j = lane + 64 * tt;
      sv[tt] = Srow[j];
      float qv = qm[j];
      l1[tt] = qv * sv[tt] + (1.f - qv) * NEGINF;
      m = fmaxf(m, l1[tt]);
    }
#pragma unroll
    for (int off = 32; off; off >>= 1) m = fmaxf(m, __shfl_xor(m, off, 64));
    float e[8], s = 0.f;
#pragma unroll
    for (int tt = 0; tt < 8; ++tt) { e[tt] = __expf(l1[tt] - m); s += e[tt]; }
#pragma unroll
    for (int off = 32; off; off >>= 1) s += __shfl_xor(s, off, 64);
    const float inv = 1.f / s;
#pragma unroll
    for (int tt = 0; tt < 8; ++tt)
      S1b[(size_t)r * LQ + lane + 64 * tt] = (__bf16)(e[tt] * inv);
    // column stats: cmv is 0/1 and wave-uniform -> skip masked rows entirely.
    if (cmv != 0.f) {
#pragma unroll
      for (int tt = 0; tt < 8; ++tt) {
        float l2 = sv[tt];
        if (l2 > colm[tt]) { cols[tt] *= __expf(colm[tt] - l2); colm[tt] = l2; }
        cols[tt] += __expf(l2 - colm[tt]);
      }
    }
  }
#pragma unroll
  for (int tt = 0; tt < 8; ++tt) cst[wv][lane + 64 * tt] = make_float2(colm[tt], cols[tt]);
  __syncthreads();
  if (tid < LQ) {
    float M = -3e38f, Sd = 0.f;
#pragma unroll
    for (int k = 0; k < 16; ++k) {
      float2 p = cst[k][tid];
      float nM = fmaxf(M, p.x);
      Sd = Sd * __expf(M - nM) + p.y * __expf(p.x - nM);
      M = nM;
    }
    pstat[((size_t)(b * 16 + ic) * LQ) + tid] = make_float2(M, Sd);
  }
}

// ---- col softmax phase 2: combine chunk stats, write TRANSPOSED S2T[j][i] ----
__global__ void k_colwrite(const float* __restrict__ S, const float* __restrict__ cmask,
                           const float2* __restrict__ pstat, __bf16* __restrict__ S2T) {
  __shared__ float Mf[64], If[64];
  __shared__ __bf16 tile[64][66];
  const int b = blockIdx.z, ic = blockIdx.y, j0 = blockIdx.x * 64;
  const int c = threadIdx.x & 63, ip = threadIdx.x >> 6;
  if (threadIdx.x < 64) {
    float M = -3e38f, Sd = 0.f;
#pragma unroll
    for (int k = 0; k < 16; ++k) {
      float2 p = pstat[((size_t)(b * 16 + k) * LQ) + j0 + threadIdx.x];
      float nM = fmaxf(M, p.x);
      Sd = Sd * __expf(M - nM) + p.y * __expf(p.x - nM);
      M = nM;
    }
    Mf[threadIdx.x] = M; If[threadIdx.x] = 1.f / Sd;
  }
  __syncthreads();
  const float M = Mf[c], inv = If[c];
  const float* Sb = S + ((size_t)b * LC + ic * 64) * LQ;
  const float* cm = cmask + b * LC + ic * 64;
  for (int r = ip; r < 64; r += 4) {
    if (cm[r] != 0.f)
      tile[r][c] = (__bf16)(__expf(Sb[(size_t)r * LQ + j0 + c] - M) * inv);
    else
      tile[r][c] = (__bf16)0.f;
  }
  __syncthreads();
  __bf16* S2Tb = S2T + ((size_t)b * LQ + j0) * LC + ic * 64;
  for (int jr = ip; jr < 64; jr += 4)
    S2Tb[(size_t)jr * LC + c] = tile[c][jr];
}

// ---------------- G2: A = S1 @ Q; epilogue also emits CA = bf16(C*A) ---------
__global__ __launch_bounds__(256) void k_mfma_A(
    const __bf16* __restrict__ S1, const __bf16* __restrict__ QT,
    const float* __restrict__ Cf, const __bf16* __restrict__ Cbfp, int use_cbf,
    __bf16* __restrict__ Aw, __bf16* __restrict__ CAw) {
  P_PROLOG
  const __bf16* Arow = S1 + (size_t)b * LC * LQ + (size_t)(i0 + srA) * LQ + swz;
  const __bf16* Brow = QT + (size_t)b * DM * LQ + (size_t)(n0 + srB) * LQ + swz;
  P_KLOOP(Arow, Brow, LQ, LQ, LQ)
  __bf16* Ab  = Aw  + (size_t)b * LC * DM;
  __bf16* CAb = CAw + (size_t)b * LC * DM;
  if (use_cbf) {
    const __bf16* Cb = Cbfp + (size_t)b * LC * DM;
#pragma unroll
    for (int x = 0; x < 4; ++x) {
      const int mB = i0 + wm * 64 + x * 16 + quad * 4;
#pragma unroll
      for (int y = 0; y < 2; ++y) {
        const int n = n0 + wn * 32 + y * 16 + col;
#pragma unroll
        for (int r = 0; r < 4; ++r) {
          const float av = acc[x][y][r];
          const float cv = (float)Cb[(size_t)(mB + r) * DM + n];
          Ab[(size_t)(mB + r) * DM + n]  = (__bf16)av;
          CAb[(size_t)(mB + r) * DM + n] = (__bf16)(av * cv);
        }
      }
    }
  } else {
    const float* Cb = Cf + (size_t)b * LC * DM;
#pragma unroll
    for (int x = 0; x < 4; ++x) {
      const int mB = i0 + wm * 64 + x * 16 + quad * 4;
#pragma unroll
      for (int y = 0; y < 2; ++y) {
        const int n = n0 + wn * 32 + y * 16 + col;
#pragma unroll
        for (int r = 0; r < 4; ++r) {
          const float av = acc[x][y][r];
          const float cv = Cb[(size_t)(mB + r) * DM + n];
          Ab[(size_t)(mB + r) * DM + n]  = (__bf16)av;
          CAb[(size_t)(mB + r) * DM + n] = (__bf16)(av * cv);
        }
      }
    }
  }
}

// ------- G3: S2TC^T[n][j]  (A=S2T rows, B=CT rows; K=Lc) ----
__global__ __launch_bounds__(256) void k_mfma_T(
    const __bf16* __restrict__ S2T, const __bf16* __restrict__ CT, __bf16* __restrict__ S2TCT) {
  P_PROLOG
  const int j0 = i0;
  const __bf16* Arow = S2T + (size_t)b * LQ * LC + (size_t)(j0 + srA) * LC + swz;
  const __bf16* Brow = CT  + (size_t)b * DM * LC + (size_t)(n0 + srB) * LC + swz;
  P_KLOOP(Arow, Brow, LC, LC, LC)
#pragma unroll
  for (int x = 0; x < 4; ++x) {
    const int jB = j0 + wm * 64 + x * 16 + quad * 4;
#pragma unroll
    for (int y = 0; y < 2; ++y) {
      const int n = n0 + wn * 32 + y * 16 + col;
      v4bf h;
#pragma unroll
      for (int r = 0; r < 4; ++r) h[r] = (__bf16)acc[x][y][r];
      *(v4bf*)&S2TCT[((size_t)b * DM + n) * LQ + jB] = h;
    }
  }
}

// ---------- G4: Bm = S1 @ S2TC; epilogue emits CB = bf16(C*Bm) only ----------
__global__ __launch_bounds__(256) void k_mfma_Bm(
    const __bf16* __restrict__ S1, const __bf16* __restrict__ S2TCT,
    const float* __restrict__ Cf, const __bf16* __restrict__ Cbfp, int use_cbf,
    __bf16* __restrict__ CBw) {
  P_PROLOG
  const __bf16* Arow = S1    + (size_t)b * LC * LQ + (size_t)(i0 + srA) * LQ + swz;
  const __bf16* Brow = S2TCT + (size_t)b * DM * LQ + (size_t)(n0 + srB) * LQ + swz;
  P_KLOOP(Arow, Brow, LQ, LQ, LQ)
  __bf16* CBb = CBw + (size_t)b * LC * DM;
  if (use_cbf) {
    const __bf16* Cb = Cbfp + (size_t)b * LC * DM;
#pragma unroll
    for (int x = 0; x < 4; ++x) {
      const int mB = i0 + wm * 64 + x * 16 + quad * 4;
#pragma unroll
      for (int y = 0; y < 2; ++y) {
        const int n = n0 + wn * 32 + y * 16 + col;
#pragma unroll
        for (int r = 0; r < 4; ++r) {
          const float cv = (float)Cb[(size_t)(mB + r) * DM + n];
          CBb[(size_t)(mB + r) * DM + n] = (__bf16)(acc[x][y][r] * cv);
        }
      }
    }
  } else {
    const float* Cb = Cf + (size_t)b * LC * DM;
#pragma unroll
    for (int x = 0; x < 4; ++x) {
      const int mB = i0 + wm * 64 + x * 16 + quad * 4;
#pragma unroll
      for (int y = 0; y < 2; ++y) {
        const int n = n0 + wn * 32 + y * 16 + col;
#pragma unroll
        for (int r = 0; r < 4; ++r) {
          const float cv = Cb[(size_t)(mB + r) * DM + n];
          CBb[(size_t)(mB + r) * DM + n] = (__bf16)(acc[x][y][r] * cv);
        }
      }
    }
  }
}

// -------- G5: out = [Cbf|Aw|CAw|CBw] @ OW^T + out_b  (pure 4-seg GEMM,
// -------- one continuous 64-step pipeline across segment boundaries) ------
__global__ __launch_bounds__(256) void k_mfma_out(
    const __bf16* __restrict__ Cb3, const __bf16* __restrict__ Aw,
    const __bf16* __restrict__ CAw, const __bf16* __restrict__ CBw,
    const __bf16* __restrict__ OWb, const float* __restrict__ ob,
    float* __restrict__ out) {
  O_PROLOG
  const size_t rowoff = (size_t)b * LC * DM + (size_t)(i0 + sr32) * DM + swz;
  const __bf16* Aseg[4] = {Cb3 + rowoff, Aw + rowoff, CAw + rowoff, CBw + rowoff};
  const __bf16* Brow0 = OWb + (size_t)(n0 + sr32) * D4 + swz;
  O_STAGE(0, Aseg[0], Brow0, DM, D4, 0);
  O_STAGE(1, Aseg[0], Brow0, DM, D4, 32);
  O_SYNC4();
  int cur_ = 0, nx2_ = 2;
#pragma unroll
  for (int seg = 0; seg < 4; ++seg) {
    const __bf16* Ac = Aseg[seg];
    const __bf16* An = Aseg[seg < 3 ? seg + 1 : 3];
    const __bf16* Bc = Brow0 + seg * DM;
    const __bf16* Bn = Brow0 + (seg < 3 ? seg + 1 : 3) * DM;
    for (int j = 0; j < 14; ++j) {          // steady: stage same-seg k+64
      O_STAGE(nx2_, Ac, Bc, DM, D4, (j + 2) * 32);
      O_COMPUTE(cur_);
      O_SYNC4();
      O_ROT();
    }
    if (seg < 3) {                          // boundary: stage next-seg k=0,32
      O_STAGE(nx2_, An, Bn, DM, D4, 0);
      O_COMPUTE(cur_);
      O_SYNC4();
      O_ROT();
      O_STAGE(nx2_, An, Bn, DM, D4, 32);
      O_COMPUTE(cur_);
      O_SYNC4();
      O_ROT();
    } else {                                // tail: steps 62, 63
      O_COMPUTE(cur_);
      O_SYNC0();
      O_ROT();
      O_COMPUTE(cur_);
    }
  }
  float* outb = out + (size_t)b * LC * DM;
#pragma unroll
  for (int x = 0; x < 4; ++x) {
    const int mB = i0 + wm * 64 + x * 16 + quad * 4;
#pragma unroll
    for (int y = 0; y < 4; ++y) {
      const int n = n0 + wn * 64 + y * 16 + col;
      const float bv = ob[n];
#pragma unroll
      for (int r = 0; r < 4; ++r)
        outb[(size_t)(mB + r) * DM + n] = acc[x][y][r] + bv;
    }
  }
}

extern "C" void kernel_launch(void* const* d_in, const int* in_sizes, int n_in,
                              void* d_out, int out_size, void* d_ws, size_t ws_size,
                              hipStream_t stream) {
  const float* C     = (const float*)d_in[0];
  const float* Q     = (const float*)d_in[1];
  const float* cmask = (const float*)d_in[2];
  const float* qmask = (const float*)d_in[3];
  const float* w     = (const float*)d_in[4];
  const float* out_w = (const float*)d_in[5];
  const float* out_b = (const float*)d_in[6];
  float* out = (float*)d_out;

  // ---- workspace carve: 128 KiB header + region R (R3 lifetime map).
  // Big-ws path (ws >= 90.125 MiB + header): Cbf persistent [72,88),
  // OWbf [88,90) -> k_cvt2b dropped; A/Bm epilogues read bf16 Cbf.
  char* base = (char*)d_ws;
  float*  cw1   = (float*)base;
  float*  qw2   = (float*)(base + 65536);
  char*   R     = base + 131072;
  float*  S     = (float*)R;                          // [0,32)   steps 2-4
  __bf16* CT    = (__bf16*)R;                         // [0,16)   steps 5-6
  __bf16* Aw    = (__bf16*)R;                         // [0,16)   steps 8-11
  __bf16* QT    = (__bf16*)(R + (16u << 20));         // [16,24)  steps 7-8
  __bf16* CBw   = (__bf16*)(R + (16u << 20));         // [16,32)  steps 9-11
  __bf16* S1    = (__bf16*)(R + (32u << 20));         // [32,48)  steps 3-9
  __bf16* Qw3   = (__bf16*)(R + (48u << 20));         // [48,56)  steps 1-2
  __bf16* S2T   = (__bf16*)(R + (48u << 20));         // [48,64)  steps 4-6
  __bf16* CAw   = (__bf16*)(R + (48u << 20));         // [48,64)  steps 8-11
  float2* pstat = (float2*)(R + (64u << 20));         // [64,65)  steps 3-4
  __bf16* S2TCT = (__bf16*)(R + (64u << 20));         // [64,72)  steps 6-9
  (void)in_sizes; (void)n_in; (void)out_size;

  const size_t need_big = 131072 + (90ull << 20);
  const bool bigws = ws_size >= need_big;

  __bf16 *Cbf, *Cbf3, *OWbf;
  if (bigws) {
    Cbf  = (__bf16*)(R + (72u << 20));                // [72,88)  persistent
    Cbf3 = Cbf;
    OWbf = (__bf16*)(R + (88u << 20));                // [88,90)  persistent
  } else {
    Cbf  = (__bf16*)(R + (32u << 20));                // [32,48)  steps 1-2 (dies to S1)
    Cbf3 = (__bf16*)(R + (32u << 20));                // [32,48)  steps 10-11 (k_cvt2b)
    OWbf = (__bf16*)(R + (64u << 20));                // [64,66)  steps 10-11 (k_cvt2b)
  }
  const int ucb = bigws ? 1 : 0;

  // 1
  k_rowdots<<<(NB * LC + NB * LQ) / 4, 256, 0, stream>>>(C, Q, w, cw1, qw2, Cbf, Qw3);
  // 2
  k_mfma_S<<<dim3(LQ / 64, LC / 128, NB), 256, 0, stream>>>(Cbf, Qw3, cw1, qw2, S);
  // 3
  k_softstat<<<dim3(LC / 64, NB), 1024, 0, stream>>>(S, qmask, cmask, S1, pstat);
  // 4
  k_colwrite<<<dim3(LQ / 64, LC / 64, NB), 256, 0, stream>>>(S, cmask, pstat, S2T);
  // 5: merged transposes (+ OW cvt in big path)
  k_prep<<<bigws ? 4096 : 3072, 256, 0, stream>>>(C, Cbf, Q, out_w, CT, QT, OWbf, ucb);
  // 6
  k_mfma_T<<<dim3(DM / 64, LQ / 128, NB), 256, 0, stream>>>(S2T, CT, S2TCT);
  // 7
  k_mfma_A<<<dim3(DM / 64, LC / 128, NB), 256, 0, stream>>>(S1, QT, C, Cbf3, ucb, Aw, CAw);
  // 8
  k_mfma_Bm<<<dim3(DM / 64, LC / 128, NB), 256, 0, stream>>>(S1, S2TCT, C, Cbf3, ucb, CBw);
  // 9 (fallback only): Cbf3 = bf16(C), OWbf = bf16(out_w)
  if (!bigws)
    k_cvt2b<<<(NB * LC * DM + DM * D4) / 1024, 256, 0, stream>>>(C, out_w, Cbf3, OWbf);
  // 10
  k_mfma_out<<<dim3(DM / 128, LC / 128, NB), 256, 0, stream>>>(Cbf3, Aw, CAw, CBw, OWbf, out_b, out);
}

// Round 10
// 275.402 us; speedup vs baseline: 1.0079x; 1.0079x over previous
//
#include <hip/hip_runtime.h>
#include <hip/hip_bf16.h>

// CQAttention: B=16, Lc=1024, Lq=512, d=512.  f32 I/O, bf16 MFMA GEMMs, f32 acc.
// Round 18: (1) revert R9's setprio (m190-style null/negative on lockstep
// GEMM; out 44.7->52) and P-core back to R8 v2 (3-buf vmcnt(3)) — R9's
// pair-phase was exactly neutral (rest 226 -> 225.6).  (2) NEW tier-3 path
// (ws >= 106.125 MiB + header): k_mfma_A + k_mfma_Bm merged into k_mfma_AB —
// shared S1 A-tile staging, both B operands (QT, S2TCT) staged per step
// (4 loads/stage = O-core's validated vmcnt(4) shape, 16 MFMA/barrier),
// epilogue reads Cbf tile once for CA and CB.  CBw relocated to [90,106) to
// break the QT[16,24)-read / CBw[16,32)-write race.  Fallback = R8 split.

#define NB 16
#define LC 1024
#define LQ 512
#define DM 512
#define D4 2048
#define NEGINF (-1e30f)

typedef __bf16 v8bf __attribute__((ext_vector_type(8)));
typedef __bf16 v4bf __attribute__((ext_vector_type(4)));
typedef float  v4f  __attribute__((ext_vector_type(4)));

#define MFMA16 __builtin_amdgcn_mfma_f32_16x16x32_bf16

// direct global->LDS async copy, 16B per lane; LDS dest is wave-uniform base.
#define GLOAD16(gp, lp) __builtin_amdgcn_global_load_lds( \
    (const __attribute__((address_space(1))) void*)(gp), \
    (__attribute__((address_space(3))) void*)(lp), 16, 0, 0)

// XCD-aware remap.
__device__ __forceinline__ void xcd_remap(int& bx, int& by, int& bz) {
  const int gx = gridDim.x, gy = gridDim.y, gz = gridDim.z;
  int flat = bx + gx * (by + gy * bz);
  int per = (gx * gy * gz) >> 3;
  int nw = (flat & 7) * per + (flat >> 3);
  bx = nw % gx;
  int r = nw / gx;
  by = r % gy;
  bz = r / gy;
}

// ========= CORE P v2 (pure GEMMs): tile 128x64, BK=32, 3-buf counted =========
// LDS row = 32 elems (64 B) = 4 chunks of 16 B; chunk c of row r stored at
// slot c ^ (r&3) ^ ((r>>2)&3).  3 gload16/thread/stage; vmcnt(3) waits only
// the stage issued two steps ago.
#define P_PROLOG \
  __shared__ __bf16 Al[3][128 * 32], Bl[3][64 * 32]; \
  int bx = blockIdx.x, by = blockIdx.y, bz = blockIdx.z; \
  xcd_remap(bx, by, bz); \
  const int b = bz, i0 = by * 128, n0 = bx * 64; \
  const int t = threadIdx.x, lane = t & 63, wave = t >> 6; \
  const int wm = wave >> 1, wn = wave & 1, quad = lane >> 4, col = lane & 15; \
  const int srA = wave * 32 + (lane >> 2); \
  const int srB = wave * 16 + (lane >> 2); \
  const int swz = (((lane & 3) ^ ((lane >> 2) & 3) ^ ((lane >> 4) & 3)) * 8); \
  const int rdx = ((quad ^ (col & 3) ^ ((col >> 2) & 3)) * 8); \
  v4f acc[4][2]; \
  _Pragma("unroll") for (int x = 0; x < 4; ++x) \
  _Pragma("unroll") for (int y = 0; y < 2; ++y) \
  _Pragma("unroll") for (int r = 0; r < 4; ++r) acc[x][y][r] = 0.f;

#define P_STAGE(buf, Aptr, Bptr, LDGA, LDGB, k0) \
  do { \
    GLOAD16((Aptr) + (k0),                       &Al[buf][(wave * 32) * 32]); \
    GLOAD16((Aptr) + (size_t)16 * (LDGA) + (k0), &Al[buf][(wave * 32 + 16) * 32]); \
    GLOAD16((Bptr) + (k0),                       &Bl[buf][(wave * 16) * 32]); \
  } while (0)

// one BK=32 step: 6 ds_read_b128 + 8 MFMA per wave.
#define P_COMPUTE(buf) \
  do { \
    v8bf af_[4], bf_[2]; \
    _Pragma("unroll") for (int x = 0; x < 4; ++x) \
      af_[x] = *(const v8bf*)&Al[buf][(wm * 64 + x * 16 + col) * 32 + rdx]; \
    _Pragma("unroll") for (int y = 0; y < 2; ++y) \
      bf_[y] = *(const v8bf*)&Bl[buf][(wn * 32 + y * 16 + col) * 32 + rdx]; \
    _Pragma("unroll") for (int x = 0; x < 4; ++x) \
    _Pragma("unroll") for (int y = 0; y < 2; ++y) \
      acc[x][y] = MFMA16(af_[x], bf_[y], acc[x][y], 0, 0, 0); \
  } while (0)

#define P_SYNC3() \
  do { asm volatile("s_waitcnt vmcnt(3)" ::: "memory"); \
       __builtin_amdgcn_s_barrier(); } while (0)
#define P_SYNC0() \
  do { asm volatile("s_waitcnt vmcnt(0)" ::: "memory"); \
       __builtin_amdgcn_s_barrier(); } while (0)

#define P_ROT() do { cur_ = (cur_ == 2) ? 0 : cur_ + 1; \
                     nx2_ = (nx2_ == 2) ? 0 : nx2_ + 1; } while (0)

// KEXT >= 96, multiple of 32.
#define P_KLOOP(Arow, Brow, LDGA, LDGB, KEXT) \
  { P_STAGE(0, Arow, Brow, LDGA, LDGB, 0); \
    P_STAGE(1, Arow, Brow, LDGA, LDGB, 32); \
    P_SYNC3(); \
    int cur_ = 0, nx2_ = 2; \
    for (int k0 = 0; k0 < (KEXT); k0 += 32) { \
      const int kn_ = k0 + 64; \
      if (kn_ < (KEXT)) { \
        P_STAGE(nx2_, Arow, Brow, LDGA, LDGB, kn_); \
        P_COMPUTE(cur_); \
        P_SYNC3(); \
      } else if (k0 + 32 < (KEXT)) { \
        P_COMPUTE(cur_); \
        P_SYNC0(); \
      } else { \
        P_COMPUTE(cur_); \
      } \
      P_ROT(); \
    } }

// ====== CORE O (k_mfma_out): tile 128x128, BK=32, 3-buf, counted vmcnt ======
#define O_PROLOG \
  __shared__ __bf16 Al[3][128 * 32], Bl[3][128 * 32]; \
  int bx = blockIdx.x, by = blockIdx.y, bz = blockIdx.z; \
  xcd_remap(bx, by, bz); \
  const int b = bz, i0 = by * 128, n0 = bx * 128; \
  const int t = threadIdx.x, lane = t & 63, wave = t >> 6; \
  const int wm = wave >> 1, wn = wave & 1, quad = lane >> 4, col = lane & 15; \
  const int sr32 = wave * 32 + (lane >> 2); \
  const int swz = (((lane & 3) ^ ((lane >> 2) & 3) ^ ((lane >> 4) & 3)) * 8); \
  const int rdx = ((quad ^ (col & 3) ^ ((col >> 2) & 3)) * 8); \
  v4f acc[4][4]; \
  _Pragma("unroll") for (int x = 0; x < 4; ++x) \
  _Pragma("unroll") for (int y = 0; y < 4; ++y) \
  _Pragma("unroll") for (int r = 0; r < 4; ++r) acc[x][y][r] = 0.f;

#define O_STAGE(buf, Aptr, Bptr, LDGA, LDGB, k0) \
  do { \
    GLOAD16((Aptr) + (k0),                       &Al[buf][(wave * 32) * 32]); \
    GLOAD16((Aptr) + (size_t)16 * (LDGA) + (k0), &Al[buf][(wave * 32 + 16) * 32]); \
    GLOAD16((Bptr) + (k0),                       &Bl[buf][(wave * 32) * 32]); \
    GLOAD16((Bptr) + (size_t)16 * (LDGB) + (k0), &Bl[buf][(wave * 32 + 16) * 32]); \
  } while (0)

#define O_COMPUTE(buf) \
  do { \
    v8bf af_[4], bf_[4]; \
    _Pragma("unroll") for (int x = 0; x < 4; ++x) \
      af_[x] = *(const v8bf*)&Al[buf][(wm * 64 + x * 16 + col) * 32 + rdx]; \
    _Pragma("unroll") for (int y = 0; y < 4; ++y) \
      bf_[y] = *(const v8bf*)&Bl[buf][(wn * 64 + y * 16 + col) * 32 + rdx]; \
    _Pragma("unroll") for (int x = 0; x < 4; ++x) \
    _Pragma("unroll") for (int y = 0; y < 4; ++y) \
      acc[x][y] = MFMA16(af_[x], bf_[y], acc[x][y], 0, 0, 0); \
  } while (0)

#define O_SYNC4() \
  do { asm volatile("s_waitcnt vmcnt(4)" ::: "memory"); \
       __builtin_amdgcn_s_barrier(); } while (0)
#define O_SYNC0() \
  do { asm volatile("s_waitcnt vmcnt(0)" ::: "memory"); \
       __builtin_amdgcn_s_barrier(); } while (0)

#define O_ROT() do { cur_ = (cur_ == 2) ? 0 : cur_ + 1; \
                     nx2_ = (nx2_ == 2) ? 0 : nx2_ + 1; } while (0)

// -------- K1: cw1[b,i] = C.w1, qw2[b,j] = Q.w2; also emits Cbf = bf16(C)
// -------- and Qw3 = bf16(Q*w3) for the pure-bf16 k_mfma_S. ----
__global__ void k_rowdots(const float* __restrict__ C, const float* __restrict__ Q,
                          const float* __restrict__ w,
                          float* __restrict__ cw1, float* __restrict__ qw2,
                          __bf16* __restrict__ Cbf, __bf16* __restrict__ Qw3) {
  const int wid = threadIdx.x >> 6, lane = threadIdx.x & 63;
  const int row = blockIdx.x * 4 + wid;
  const bool isC = row < NB * LC;
  const int lr = isC ? row : row - NB * LC;
  const float* src = (isC ? C : Q) + (size_t)lr * DM;
  const float* wv  = isC ? w : (w + DM);
  const float* w3  = w + 2 * DM;
  __bf16* dst = (isC ? Cbf : Qw3) + (size_t)lr * DM;
  float v = 0.f;
#pragma unroll
  for (int s = 0; s < 2; ++s) {
    const int k = lane * 4 + s * 256;
    float4 f = *(const float4*)(src + k);
    float4 g = *(const float4*)(wv + k);
    v += f.x * g.x + f.y * g.y + f.z * g.z + f.w * g.w;
    v4bf h;
    if (isC) {
      h[0] = (__bf16)f.x; h[1] = (__bf16)f.y; h[2] = (__bf16)f.z; h[3] = (__bf16)f.w;
    } else {
      float4 s3 = *(const float4*)(w3 + k);
      h[0] = (__bf16)(f.x * s3.x); h[1] = (__bf16)(f.y * s3.y);
      h[2] = (__bf16)(f.z * s3.z); h[3] = (__bf16)(f.w * s3.w);
    }
    *(v4bf*)(dst + k) = h;
  }
#pragma unroll
  for (int off = 32; off; off >>= 1) v += __shfl_down(v, off, 64);
  if (lane == 0) {
    if (isC) cw1[row] = v;
    else     qw2[lr] = v;
  }
}

// ------- transpose cores: in[R][Cd] -> bf16 outT[Cd][R], one 64x64 tile ----
__device__ __forceinline__ void transpose_tile_f32(const float* __restrict__ in,
                                                   __bf16* __restrict__ outT,
                                                   int R, int Cd, int tbx, int tby, int tb) {
  __shared__ __bf16 tile[64][66];
  const int r0 = tby * 64, c0 = tbx * 64;
  const int tr = threadIdx.x >> 6, tc = threadIdx.x & 63;
  const float* inb = in + (size_t)tb * R * Cd;
  __bf16* outb = outT + (size_t)tb * Cd * R;
  for (int r = tr; r < 64; r += 4)
    tile[r][tc] = (__bf16)inb[(size_t)(r0 + r) * Cd + c0 + tc];
  __syncthreads();
  for (int c = tr; c < 64; c += 4)
    outb[(size_t)(c0 + c) * R + r0 + tc] = tile[tc][c];
}

__device__ __forceinline__ void transpose_tile_bf(const __bf16* __restrict__ in,
                                                  __bf16* __restrict__ outT,
                                                  int R, int Cd, int tbx, int tby, int tb) {
  __shared__ __bf16 tile[64][66];
  const int r0 = tby * 64, c0 = tbx * 64;
  const int tr = threadIdx.x >> 6, tc = threadIdx.x & 63;
  const __bf16* inb = in + (size_t)tb * R * Cd;
  __bf16* outb = outT + (size_t)tb * Cd * R;
  for (int r = tr; r < 64; r += 4)
    tile[r][tc] = inb[(size_t)(r0 + r) * Cd + c0 + tc];
  __syncthreads();
  for (int c = tr; c < 64; c += 4)
    outb[(size_t)(c0 + c) * R + r0 + tc] = tile[tc][c];
}

// ------- merged prep: transpose C (2048 blks, from Cbf when available) +
// ------- transpose Q (1024 blks) [+ OW cvt (1024 blks) in big-ws path] ----
__global__ void k_prep(const float* __restrict__ C, const __bf16* __restrict__ Cbf,
                       const float* __restrict__ Q, const float* __restrict__ OW,
                       __bf16* __restrict__ CT, __bf16* __restrict__ QT,
                       __bf16* __restrict__ OWb, int use_cbf) {
  const int id = blockIdx.x;
  if (id < 2048) {                      // C^T: (8, 16, 16)
    if (use_cbf) transpose_tile_bf(Cbf, CT, LC, DM, id & 7, (id >> 3) & 15, id >> 7);
    else         transpose_tile_f32(C,  CT, LC, DM, id & 7, (id >> 3) & 15, id >> 7);
  } else if (id < 3072) {               // Q^T: (8, 8, 16)
    const int id2 = id - 2048;
    transpose_tile_f32(Q, QT, LQ, DM, id2 & 7, (id2 >> 3) & 7, id2 >> 6);
  } else {                              // OW cvt: 1024 blocks x 1024 elems
    const size_t i = ((size_t)(id - 3072) * 256 + threadIdx.x) * 4;
    float4 f = *(const float4*)(OW + i);
    v4bf h; h[0] = (__bf16)f.x; h[1] = (__bf16)f.y; h[2] = (__bf16)f.z; h[3] = (__bf16)f.w;
    *(v4bf*)(OWb + i) = h;
  }
}

// ------- fallback late cvt: Cbf3 = bf16(C) and OWbf = bf16(out_w) -------
__global__ void k_cvt2b(const float* __restrict__ Cf, const float* __restrict__ OW,
                        __bf16* __restrict__ Cb3, __bf16* __restrict__ OWb) {
  const size_t NC = (size_t)NB * LC * DM;
  size_t i = ((size_t)blockIdx.x * 256 + threadIdx.x) * 4;
  if (i < NC) {
    float4 f = *(const float4*)(Cf + i);
    v4bf h; h[0] = (__bf16)f.x; h[1] = (__bf16)f.y; h[2] = (__bf16)f.z; h[3] = (__bf16)f.w;
    *(v4bf*)(Cb3 + i) = h;
  } else {
    size_t j = i - NC;
    float4 f = *(const float4*)(OW + j);
    v4bf h; h[0] = (__bf16)f.x; h[1] = (__bf16)f.y; h[2] = (__bf16)f.z; h[3] = (__bf16)f.w;
    *(v4bf*)(OWb + j) = h;
  }
}

// ---------------- G1: S = cw1 + qw2 + Cbf @ Qw3^T ----------------
__global__ __launch_bounds__(256) void k_mfma_S(
    const __bf16* __restrict__ Cbf, const __bf16* __restrict__ Qw3,
    const float* __restrict__ cw1, const float* __restrict__ qw2,
    float* __restrict__ S) {
  P_PROLOG
  const __bf16* Arow = Cbf + (size_t)b * LC * DM + (size_t)(i0 + srA) * DM + swz;
  const __bf16* Brow = Qw3 + (size_t)b * LQ * DM + (size_t)(n0 + srB) * DM + swz;
  P_KLOOP(Arow, Brow, DM, DM, DM)
  float* Sb = S + (size_t)b * LC * LQ;
#pragma unroll
  for (int x = 0; x < 4; ++x) {
    const int mB = i0 + wm * 64 + x * 16 + quad * 4;
    float cv[4];
#pragma unroll
    for (int r = 0; r < 4; ++r) cv[r] = cw1[b * LC + mB + r];
#pragma unroll
    for (int y = 0; y < 2; ++y) {
      const int j = n0 + wn * 32 + y * 16 + col;
      const float qv = qw2[b * LQ + j];
#pragma unroll
      for (int r = 0; r < 4; ++r)
        Sb[(size_t)(mB + r) * LQ + j] = acc[x][y][r] + cv[r] + qv;
    }
  }
}

// ---- fused: row softmax (qmask) -> S1  AND  per-64i-chunk column stats ----
__global__ __launch_bounds__(1024) void k_softstat(
    const float* __restrict__ S, const float* __restrict__ qmask,
    const float* __restrict__ cmask, __bf16* __restrict__ S1,
    float2* __restrict__ pstat) {
  __shared__ float2 cst[16][LQ];
  const int b = blockIdx.y, ic = blockIdx.x;
  const int tid = threadIdx.x, wv = tid >> 6, lane = tid & 63;
  const float* qm  = qmask + b * LQ;
  const float* cm  = cmask + b * LC + ic * 64;
  const float* Sb  = S  + ((size_t)b * LC + ic * 64) * LQ;
  __bf16*      S1b = S1 + ((size_t)b * LC + ic * 64) * LQ;
  float colm[8], cols[8];
#pragma unroll
  for (int tt = 0; tt < 8; ++tt) { colm[tt] = -3e38f; cols[tt] = 0.f; }
  for (int it = 0; it < 4; ++it) {
    const int r = wv * 4 + it;
    const float cmv = cm[r];
    const float* Srow = Sb + (size_t)r * LQ;
    float sv[8], l1[8];
    float m = -3e38f;
#pragma unroll
    for (int tt = 0; tt < 8; ++tt) {
      int j = lane + 64 * tt;
      sv[tt] = Srow[j];
      float qv = qm[j];
      l1[tt] = qv * sv[tt] + (1.f - qv) * NEGINF;
      m = fmaxf(m, l1[tt]);
    }
#pragma unroll
    for (int off = 32; off; off >>= 1) m = fmaxf(m, __shfl_xor(m, off, 64));
    float e[8], s = 0.f;
#pragma unroll
    for (int tt = 0; tt < 8; ++tt) { e[tt] = __expf(l1[tt] - m); s += e[tt]; }
#pragma unroll
    for (int off = 32; off; off >>= 1) s += __shfl_xor(s, off, 64);
    const float inv = 1.f / s;
#pragma unroll
    for (int tt = 0; tt < 8; ++tt)
      S1b[(size_t)r * LQ + lane + 64 * tt] = (__bf16)(e[tt] * inv);
    // column stats: cmv is 0/1 and wave-uniform -> skip masked rows entirely.
    if (cmv != 0.f) {
#pragma unroll
      for (int tt = 0; tt < 8; ++tt) {
        float l2 = sv[tt];
        if (l2 > colm[tt]) { cols[tt] *= __expf(colm[tt] - l2); colm[tt] = l2; }
        cols[tt] += __expf(l2 - colm[tt]);
      }
    }
  }
#pragma unroll
  for (int tt = 0; tt < 8; ++tt) cst[wv][lane + 64 * tt] = make_float2(colm[tt], cols[tt]);
  __syncthreads();
  if (tid < LQ) {
    float M = -3e38f, Sd = 0.f;
#pragma unroll
    for (int k = 0; k < 16; ++k) {
      float2 p = cst[k][tid];
      float nM = fmaxf(M, p.x);
      Sd = Sd * __expf(M - nM) + p.y * __expf(p.x - nM);
      M = nM;
    }
    pstat[((size_t)(b * 16 + ic) * LQ) + tid] = make_float2(M, Sd);
  }
}

// ---- col softmax phase 2: combine chunk stats, write TRANSPOSED S2T[j][i] ----
__global__ void k_colwrite(const float* __restrict__ S, const float* __restrict__ cmask,
                           const float2* __restrict__ pstat, __bf16* __restrict__ S2T) {
  __shared__ float Mf[64], If[64];
  __shared__ __bf16 tile[64][66];
  const int b = blockIdx.z, ic = blockIdx.y, j0 = blockIdx.x * 64;
  const int c = threadIdx.x & 63, ip = threadIdx.x >> 6;
  if (threadIdx.x < 64) {
    float M = -3e38f, Sd = 0.f;
#pragma unroll
    for (int k = 0; k < 16; ++k) {
      float2 p = pstat[((size_t)(b * 16 + k) * LQ) + j0 + threadIdx.x];
      float nM = fmaxf(M, p.x);
      Sd = Sd * __expf(M - nM) + p.y * __expf(p.x - nM);
      M = nM;
    }
    Mf[threadIdx.x] = M; If[threadIdx.x] = 1.f / Sd;
  }
  __syncthreads();
  const float M = Mf[c], inv = If[c];
  const float* Sb = S + ((size_t)b * LC + ic * 64) * LQ;
  const float* cm = cmask + b * LC + ic * 64;
  for (int r = ip; r < 64; r += 4) {
    if (cm[r] != 0.f)
      tile[r][c] = (__bf16)(__expf(Sb[(size_t)r * LQ + j0 + c] - M) * inv);
    else
      tile[r][c] = (__bf16)0.f;
  }
  __syncthreads();
  __bf16* S2Tb = S2T + ((size_t)b * LQ + j0) * LC + ic * 64;
  for (int jr = ip; jr < 64; jr += 4)
    S2Tb[(size_t)jr * LC + c] = tile[c][jr];
}

// ---------------- G2: A = S1 @ Q; epilogue also emits CA = bf16(C*A) ---------
__global__ __launch_bounds__(256) void k_mfma_A(
    const __bf16* __restrict__ S1, const __bf16* __restrict__ QT,
    const float* __restrict__ Cf, const __bf16* __restrict__ Cbfp, int use_cbf,
    __bf16* __restrict__ Aw, __bf16* __restrict__ CAw) {
  P_PROLOG
  const __bf16* Arow = S1 + (size_t)b * LC * LQ + (size_t)(i0 + srA) * LQ + swz;
  const __bf16* Brow = QT + (size_t)b * DM * LQ + (size_t)(n0 + srB) * LQ + swz;
  P_KLOOP(Arow, Brow, LQ, LQ, LQ)
  __bf16* Ab  = Aw  + (size_t)b * LC * DM;
  __bf16* CAb = CAw + (size_t)b * LC * DM;
  if (use_cbf) {
    const __bf16* Cb = Cbfp + (size_t)b * LC * DM;
#pragma unroll
    for (int x = 0; x < 4; ++x) {
      const int mB = i0 + wm * 64 + x * 16 + quad * 4;
#pragma unroll
      for (int y = 0; y < 2; ++y) {
        const int n = n0 + wn * 32 + y * 16 + col;
#pragma unroll
        for (int r = 0; r < 4; ++r) {
          const float av = acc[x][y][r];
          const float cv = (float)Cb[(size_t)(mB + r) * DM + n];
          Ab[(size_t)(mB + r) * DM + n]  = (__bf16)av;
          CAb[(size_t)(mB + r) * DM + n] = (__bf16)(av * cv);
        }
      }
    }
  } else {
    const float* Cb = Cf + (size_t)b * LC * DM;
#pragma unroll
    for (int x = 0; x < 4; ++x) {
      const int mB = i0 + wm * 64 + x * 16 + quad * 4;
#pragma unroll
      for (int y = 0; y < 2; ++y) {
        const int n = n0 + wn * 32 + y * 16 + col;
#pragma unroll
        for (int r = 0; r < 4; ++r) {
          const float av = acc[x][y][r];
          const float cv = Cb[(size_t)(mB + r) * DM + n];
          Ab[(size_t)(mB + r) * DM + n]  = (__bf16)av;
          CAb[(size_t)(mB + r) * DM + n] = (__bf16)(av * cv);
        }
      }
    }
  }
}

// ------- G3: S2TC^T[n][j]  (A=S2T rows, B=CT rows; K=Lc) ----
__global__ __launch_bounds__(256) void k_mfma_T(
    const __bf16* __restrict__ S2T, const __bf16* __restrict__ CT, __bf16* __restrict__ S2TCT) {
  P_PROLOG
  const int j0 = i0;
  const __bf16* Arow = S2T + (size_t)b * LQ * LC + (size_t)(j0 + srA) * LC + swz;
  const __bf16* Brow = CT  + (size_t)b * DM * LC + (size_t)(n0 + srB) * LC + swz;
  P_KLOOP(Arow, Brow, LC, LC, LC)
#pragma unroll
  for (int x = 0; x < 4; ++x) {
    const int jB = j0 + wm * 64 + x * 16 + quad * 4;
#pragma unroll
    for (int y = 0; y < 2; ++y) {
      const int n = n0 + wn * 32 + y * 16 + col;
      v4bf h;
#pragma unroll
      for (int r = 0; r < 4; ++r) h[r] = (__bf16)acc[x][y][r];
      *(v4bf*)&S2TCT[((size_t)b * DM + n) * LQ + jB] = h;
    }
  }
}

// ---------- G4: Bm = S1 @ S2TC; epilogue emits CB = bf16(C*Bm) only ----------
__global__ __launch_bounds__(256) void k_mfma_Bm(
    const __bf16* __restrict__ S1, const __bf16* __restrict__ S2TCT,
    const float* __restrict__ Cf, const __bf16* __restrict__ Cbfp, int use_cbf,
    __bf16* __restrict__ CBw) {
  P_PROLOG
  const __bf16* Arow = S1    + (size_t)b * LC * LQ + (size_t)(i0 + srA) * LQ + swz;
  const __bf16* Brow = S2TCT + (size_t)b * DM * LQ + (size_t)(n0 + srB) * LQ + swz;
  P_KLOOP(Arow, Brow, LQ, LQ, LQ)
  __bf16* CBb = CBw + (size_t)b * LC * DM;
  if (use_cbf) {
    const __bf16* Cb = Cbfp + (size_t)b * LC * DM;
#pragma unroll
    for (int x = 0; x < 4; ++x) {
      const int mB = i0 + wm * 64 + x * 16 + quad * 4;
#pragma unroll
      for (int y = 0; y < 2; ++y) {
        const int n = n0 + wn * 32 + y * 16 + col;
#pragma unroll
        for (int r = 0; r < 4; ++r) {
          const float cv = (float)Cb[(size_t)(mB + r) * DM + n];
          CBb[(size_t)(mB + r) * DM + n] = (__bf16)(acc[x][y][r] * cv);
        }
      }
    }
  } else {
    const float* Cb = Cf + (size_t)b * LC * DM;
#pragma unroll
    for (int x = 0; x < 4; ++x) {
      const int mB = i0 + wm * 64 + x * 16 + quad * 4;
#pragma unroll
      for (int y = 0; y < 2; ++y) {
        const int n = n0 + wn * 32 + y * 16 + col;
#pragma unroll
        for (int r = 0; r < 4; ++r) {
          const float cv = Cb[(size_t)(mB + r) * DM + n];
          CBb[(size_t)(mB + r) * DM + n] = (__bf16)(acc[x][y][r] * cv);
        }
      }
    }
  }
}

// ---- G2+G4 merged (tier3): A = S1@Q and Bm = S1@S2TC with SHARED S1 tile ----
// 4 gload16/thread/stage (= O-core's validated vmcnt(4) shape), 16 MFMA/step.
// Epilogue reads the Cbf tile once for both CA and CB.
__global__ __launch_bounds__(256) void k_mfma_AB(
    const __bf16* __restrict__ S1, const __bf16* __restrict__ QT,
    const __bf16* __restrict__ S2TCT, const __bf16* __restrict__ Cbfp,
    __bf16* __restrict__ Aw, __bf16* __restrict__ CAw, __bf16* __restrict__ CBw) {
  __shared__ __bf16 Al[3][128 * 32], BlQ[3][64 * 32], BlS[3][64 * 32];
  int bx = blockIdx.x, by = blockIdx.y, bz = blockIdx.z;
  xcd_remap(bx, by, bz);
  const int b = bz, i0 = by * 128, n0 = bx * 64;
  const int t = threadIdx.x, lane = t & 63, wave = t >> 6;
  const int wm = wave >> 1, wn = wave & 1, quad = lane >> 4, col = lane & 15;
  const int srA = wave * 32 + (lane >> 2);
  const int srB = wave * 16 + (lane >> 2);
  const int swz = (((lane & 3) ^ ((lane >> 2) & 3) ^ ((lane >> 4) & 3)) * 8);
  const int rdx = ((quad ^ (col & 3) ^ ((col >> 2) & 3)) * 8);
  v4f accA[4][2], accB[4][2];
#pragma unroll
  for (int x = 0; x < 4; ++x)
#pragma unroll
    for (int y = 0; y < 2; ++y)
#pragma unroll
      for (int r = 0; r < 4; ++r) { accA[x][y][r] = 0.f; accB[x][y][r] = 0.f; }
  const __bf16* Arow  = S1    + (size_t)b * LC * LQ + (size_t)(i0 + srA) * LQ + swz;
  const __bf16* BrowQ = QT    + (size_t)b * DM * LQ + (size_t)(n0 + srB) * LQ + swz;
  const __bf16* BrowS = S2TCT + (size_t)b * DM * LQ + (size_t)(n0 + srB) * LQ + swz;

#define AB_STAGE(buf, k0) \
  do { \
    GLOAD16(Arow + (k0),                      &Al[buf][(wave * 32) * 32]); \
    GLOAD16(Arow + (size_t)16 * LQ + (k0),    &Al[buf][(wave * 32 + 16) * 32]); \
    GLOAD16(BrowQ + (k0),                     &BlQ[buf][(wave * 16) * 32]); \
    GLOAD16(BrowS + (k0),                     &BlS[buf][(wave * 16) * 32]); \
  } while (0)

#define AB_COMPUTE(buf) \
  do { \
    v8bf af_[4], bq_[2], bs_[2]; \
    _Pragma("unroll") for (int x = 0; x < 4; ++x) \
      af_[x] = *(const v8bf*)&Al[buf][(wm * 64 + x * 16 + col) * 32 + rdx]; \
    _Pragma("unroll") for (int y = 0; y < 2; ++y) { \
      bq_[y] = *(const v8bf*)&BlQ[buf][(wn * 32 + y * 16 + col) * 32 + rdx]; \
      bs_[y] = *(const v8bf*)&BlS[buf][(wn * 32 + y * 16 + col) * 32 + rdx]; \
    } \
    _Pragma("unroll") for (int x = 0; x < 4; ++x) \
    _Pragma("unroll") for (int y = 0; y < 2; ++y) { \
      accA[x][y] = MFMA16(af_[x], bq_[y], accA[x][y], 0, 0, 0); \
      accB[x][y] = MFMA16(af_[x], bs_[y], accB[x][y], 0, 0, 0); \
    } \
  } while (0)

  AB_STAGE(0, 0);
  AB_STAGE(1, 32);
  asm volatile("s_waitcnt vmcnt(4)" ::: "memory");
  __builtin_amdgcn_s_barrier();
  int cur_ = 0, nx2_ = 2;
  for (int k0 = 0; k0 < LQ; k0 += 32) {
    const int kn_ = k0 + 64;
    if (kn_ < LQ) {
      AB_STAGE(nx2_, kn_);
      AB_COMPUTE(cur_);
      asm volatile("s_waitcnt vmcnt(4)" ::: "memory");
      __builtin_amdgcn_s_barrier();
    } else if (k0 + 32 < LQ) {
      AB_COMPUTE(cur_);
      asm volatile("s_waitcnt vmcnt(0)" ::: "memory");
      __builtin_amdgcn_s_barrier();
    } else {
      AB_COMPUTE(cur_);
    }
    cur_ = (cur_ == 2) ? 0 : cur_ + 1;
    nx2_ = (nx2_ == 2) ? 0 : nx2_ + 1;
  }
#undef AB_STAGE
#undef AB_COMPUTE

  __bf16* Ab  = Aw  + (size_t)b * LC * DM;
  __bf16* CAb = CAw + (size_t)b * LC * DM;
  __bf16* CBb = CBw + (size_t)b * LC * DM;
  const __bf16* Cb = Cbfp + (size_t)b * LC * DM;
#pragma unroll
  for (int x = 0; x < 4; ++x) {
    const int mB = i0 + wm * 64 + x * 16 + quad * 4;
#pragma unroll
    for (int y = 0; y < 2; ++y) {
      const int n = n0 + wn * 32 + y * 16 + col;
#pragma unroll
      for (int r = 0; r < 4; ++r) {
        const float av = accA[x][y][r];
        const float bv = accB[x][y][r];
        const float cv = (float)Cb[(size_t)(mB + r) * DM + n];
        Ab[(size_t)(mB + r) * DM + n]  = (__bf16)av;
        CAb[(size_t)(mB + r) * DM + n] = (__bf16)(av * cv);
        CBb[(size_t)(mB + r) * DM + n] = (__bf16)(bv * cv);
      }
    }
  }
}

// -------- G5: out = [Cbf|Aw|CAw|CBw] @ OW^T + out_b  (pure 4-seg GEMM,
// -------- one continuous 64-step pipeline across segment boundaries) ------
__global__ __launch_bounds__(256) void k_mfma_out(
    const __bf16* __restrict__ Cb3, const __bf16* __restrict__ Aw,
    const __bf16* __restrict__ CAw, const __bf16* __restrict__ CBw,
    const __bf16* __restrict__ OWb, const float* __restrict__ ob,
    float* __restrict__ out) {
  O_PROLOG
  const size_t rowoff = (size_t)b * LC * DM + (size_t)(i0 + sr32) * DM + swz;
  const __bf16* Aseg[4] = {Cb3 + rowoff, Aw + rowoff, CAw + rowoff, CBw + rowoff};
  const __bf16* Brow0 = OWb + (size_t)(n0 + sr32) * D4 + swz;
  O_STAGE(0, Aseg[0], Brow0, DM, D4, 0);
  O_STAGE(1, Aseg[0], Brow0, DM, D4, 32);
  O_SYNC4();
  int cur_ = 0, nx2_ = 2;
#pragma unroll
  for (int seg = 0; seg < 4; ++seg) {
    const __bf16* Ac = Aseg[seg];
    const __bf16* An = Aseg[seg < 3 ? seg + 1 : 3];
    const __bf16* Bc = Brow0 + seg * DM;
    const __bf16* Bn = Brow0 + (seg < 3 ? seg + 1 : 3) * DM;
    for (int j = 0; j < 14; ++j) {          // steady: stage same-seg k+64
      O_STAGE(nx2_, Ac, Bc, DM, D4, (j + 2) * 32);
      O_COMPUTE(cur_);
      O_SYNC4();
      O_ROT();
    }
    if (seg < 3) {                          // boundary: stage next-seg k=0,32
      O_STAGE(nx2_, An, Bn, DM, D4, 0);
      O_COMPUTE(cur_);
      O_SYNC4();
      O_ROT();
      O_STAGE(nx2_, An, Bn, DM, D4, 32);
      O_COMPUTE(cur_);
      O_SYNC4();
      O_ROT();
    } else {                                // tail: steps 62, 63
      O_COMPUTE(cur_);
      O_SYNC0();
      O_ROT();
      O_COMPUTE(cur_);
    }
  }
  float* outb = out + (size_t)b * LC * DM;
#pragma unroll
  for (int x = 0; x < 4; ++x) {
    const int mB = i0 + wm * 64 + x * 16 + quad * 4;
#pragma unroll
    for (int y = 0; y < 4; ++y) {
      const int n = n0 + wn * 64 + y * 16 + col;
      const float bv = ob[n];
#pragma unroll
      for (int r = 0; r < 4; ++r)
        outb[(size_t)(mB + r) * DM + n] = acc[x][y][r] + bv;
    }
  }
}

extern "C" void kernel_launch(void* const* d_in, const int* in_sizes, int n_in,
                              void* d_out, int out_size, void* d_ws, size_t ws_size,
                              hipStream_t stream) {
  const float* C     = (const float*)d_in[0];
  const float* Q     = (const float*)d_in[1];
  const float* cmask = (const float*)d_in[2];
  const float* qmask = (const float*)d_in[3];
  const float* w     = (const float*)d_in[4];
  const float* out_w = (const float*)d_in[5];
  const float* out_b = (const float*)d_in[6];
  float* out = (float*)d_out;

  // ---- workspace carve: 128 KiB header + region R (R3 lifetime map).
  // tier2 (ws >= 90.125 MiB): Cbf persistent [72,88), OWbf [88,90).
  // tier3 (ws >= 106.125 MiB): additionally CBw at [90,106) -> merged AB.
  char* base = (char*)d_ws;
  float*  cw1   = (float*)base;
  float*  qw2   = (float*)(base + 65536);
  char*   R     = base + 131072;
  float*  S     = (float*)R;                          // [0,32)   steps 2-4
  __bf16* CT    = (__bf16*)R;                         // [0,16)   steps 5-6
  __bf16* Aw    = (__bf16*)R;                         // [0,16)   steps 8-11
  __bf16* QT    = (__bf16*)(R + (16u << 20));         // [16,24)  steps 7-8
  __bf16* S1    = (__bf16*)(R + (32u << 20));         // [32,48)  steps 3-9
  __bf16* Qw3   = (__bf16*)(R + (48u << 20));         // [48,56)  steps 1-2
  __bf16* S2T   = (__bf16*)(R + (48u << 20));         // [48,64)  steps 4-6
  __bf16* CAw   = (__bf16*)(R + (48u << 20));         // [48,64)  steps 8-11
  float2* pstat = (float2*)(R + (64u << 20));         // [64,65)  steps 3-4
  __bf16* S2TCT = (__bf16*)(R + (64u << 20));         // [64,72)  steps 6-9
  (void)in_sizes; (void)n_in; (void)out_size;

  const bool bigws = ws_size >= 131072 + (90ull << 20);
  const bool tier3 = ws_size >= 131072 + (106ull << 20);

  __bf16 *Cbf, *Cbf3, *OWbf, *CBw;
  if (bigws) {
    Cbf  = (__bf16*)(R + (72u << 20));                // [72,88)  persistent
    Cbf3 = Cbf;
    OWbf = (__bf16*)(R + (88u << 20));                // [88,90)  persistent
  } else {
    Cbf  = (__bf16*)(R + (32u << 20));                // [32,48)  steps 1-2 (dies to S1)
    Cbf3 = (__bf16*)(R + (32u << 20));                // [32,48)  steps 10-11 (k_cvt2b)
    OWbf = (__bf16*)(R + (64u << 20));                // [64,66)  steps 10-11 (k_cvt2b)
  }
  CBw = tier3 ? (__bf16*)(R + (90u << 20))            // [90,106) tier3 (AB-merge safe)
              : (__bf16*)(R + (16u << 20));           // [16,32)  split path (after QT dies)
  const int ucb = bigws ? 1 : 0;

  // 1
  k_rowdots<<<(NB * LC + NB * LQ) / 4, 256, 0, stream>>>(C, Q, w, cw1, qw2, Cbf, Qw3);
  // 2
  k_mfma_S<<<dim3(LQ / 64, LC / 128, NB), 256, 0, stream>>>(Cbf, Qw3, cw1, qw2, S);
  // 3
  k_softstat<<<dim3(LC / 64, NB), 1024, 0, stream>>>(S, qmask, cmask, S1, pstat);
  // 4
  k_colwrite<<<dim3(LQ / 64, LC / 64, NB), 256, 0, stream>>>(S, cmask, pstat, S2T);
  // 5: merged transposes (+ OW cvt in big path)
  k_prep<<<bigws ? 4096 : 3072, 256, 0, stream>>>(C, Cbf, Q, out_w, CT, QT, OWbf, ucb);
  // 6
  k_mfma_T<<<dim3(DM / 64, LQ / 128, NB), 256, 0, stream>>>(S2T, CT, S2TCT);
  // 7/8
  if (tier3) {
    k_mfma_AB<<<dim3(DM / 64, LC / 128, NB), 256, 0, stream>>>(
        S1, QT, S2TCT, Cbf, Aw, CAw, CBw);
  } else {
    k_mfma_A<<<dim3(DM / 64, LC / 128, NB), 256, 0, stream>>>(S1, QT, C, Cbf3, ucb, Aw, CAw);
    k_mfma_Bm<<<dim3(DM / 64, LC / 128, NB), 256, 0, stream>>>(S1, S2TCT, C, Cbf3, ucb, CBw);
  }
  // 9 (fallback only): Cbf3 = bf16(C), OWbf = bf16(out_w)
  if (!bigws)
    k_cvt2b<<<(NB * LC * DM + DM * D4) / 1024, 256, 0, stream>>>(C, out_w, Cbf3, OWbf);
  // 10
  k_mfma_out<<<dim3(DM / 128, LC / 128, NB), 256, 0, stream>>>(Cbf3, Aw, CAw, CBw, OWbf, out_b, out);
}

// Round 11
// 268.138 us; speedup vs baseline: 1.0352x; 1.0271x over previous
//
#include <hip/hip_runtime.h>
#include <hip/hip_bf16.h>

// CQAttention: B=16, Lc=1024, Lq=512, d=512.  f32 I/O, bf16 MFMA GEMMs, f32 acc.
// Round 19: LOCK-IN of the measured-argmax configuration (R8 = 270.66 us).
// Methodological fix: rocprof per-kernel durations come from separate profiled
// runs at independent DVFS states (identical out binary read 44.5 us in R6/R8,
// 66 us in R7/R10 with time/MfmaUtil/VALUBusy scaling uniformly) — so
// "rest = total - rocprof_out" decompositions across rounds were noise.  By
// bench totals alone: P-schedule variants (2buf/3buf/pair-phase), setprio,
// cbf-epilogues, tier3 AB-merge are all within the +-5-7 us band or negative.
// This file is the R8 source verbatim: P-core v2 (128x64, BK=32, 3-buf,
// counted vmcnt(3)), O-core (128x128, BK=32, 3-buf, counted vmcnt(4), no
// setprio), f32-C epilogues, tier2 ws gate (persistent Cbf/OWbf >= 90.125 MiB).

#define NB 16
#define LC 1024
#define LQ 512
#define DM 512
#define D4 2048
#define NEGINF (-1e30f)

typedef __bf16 v8bf __attribute__((ext_vector_type(8)));
typedef __bf16 v4bf __attribute__((ext_vector_type(4)));
typedef float  v4f  __attribute__((ext_vector_type(4)));

#define MFMA16 __builtin_amdgcn_mfma_f32_16x16x32_bf16

// direct global->LDS async copy, 16B per lane; LDS dest is wave-uniform base.
#define GLOAD16(gp, lp) __builtin_amdgcn_global_load_lds( \
    (const __attribute__((address_space(1))) void*)(gp), \
    (__attribute__((address_space(3))) void*)(lp), 16, 0, 0)

// XCD-aware remap.
__device__ __forceinline__ void xcd_remap(int& bx, int& by, int& bz) {
  const int gx = gridDim.x, gy = gridDim.y, gz = gridDim.z;
  int flat = bx + gx * (by + gy * bz);
  int per = (gx * gy * gz) >> 3;
  int nw = (flat & 7) * per + (flat >> 3);
  bx = nw % gx;
  int r = nw / gx;
  by = r % gy;
  bz = r / gy;
}

// ========= CORE P v2 (pure GEMMs): tile 128x64, BK=32, 3-buf counted =========
// LDS row = 32 elems (64 B) = 4 chunks of 16 B; chunk c of row r stored at
// slot c ^ (r&3) ^ ((r>>2)&3).  3 gload16/thread/stage; vmcnt(3) waits only
// the stage issued two steps ago; prefetch stays in flight across the barrier.
#define P_PROLOG \
  __shared__ __bf16 Al[3][128 * 32], Bl[3][64 * 32]; \
  int bx = blockIdx.x, by = blockIdx.y, bz = blockIdx.z; \
  xcd_remap(bx, by, bz); \
  const int b = bz, i0 = by * 128, n0 = bx * 64; \
  const int t = threadIdx.x, lane = t & 63, wave = t >> 6; \
  const int wm = wave >> 1, wn = wave & 1, quad = lane >> 4, col = lane & 15; \
  const int srA = wave * 32 + (lane >> 2); \
  const int srB = wave * 16 + (lane >> 2); \
  const int swz = (((lane & 3) ^ ((lane >> 2) & 3) ^ ((lane >> 4) & 3)) * 8); \
  const int rdx = ((quad ^ (col & 3) ^ ((col >> 2) & 3)) * 8); \
  v4f acc[4][2]; \
  _Pragma("unroll") for (int x = 0; x < 4; ++x) \
  _Pragma("unroll") for (int y = 0; y < 2; ++y) \
  _Pragma("unroll") for (int r = 0; r < 4; ++r) acc[x][y][r] = 0.f;

#define P_STAGE(buf, Aptr, Bptr, LDGA, LDGB, k0) \
  do { \
    GLOAD16((Aptr) + (k0),                       &Al[buf][(wave * 32) * 32]); \
    GLOAD16((Aptr) + (size_t)16 * (LDGA) + (k0), &Al[buf][(wave * 32 + 16) * 32]); \
    GLOAD16((Bptr) + (k0),                       &Bl[buf][(wave * 16) * 32]); \
  } while (0)

// one BK=32 step: 6 ds_read_b128 + 8 MFMA per wave.
#define P_COMPUTE(buf) \
  do { \
    v8bf af_[4], bf_[2]; \
    _Pragma("unroll") for (int x = 0; x < 4; ++x) \
      af_[x] = *(const v8bf*)&Al[buf][(wm * 64 + x * 16 + col) * 32 + rdx]; \
    _Pragma("unroll") for (int y = 0; y < 2; ++y) \
      bf_[y] = *(const v8bf*)&Bl[buf][(wn * 32 + y * 16 + col) * 32 + rdx]; \
    _Pragma("unroll") for (int x = 0; x < 4; ++x) \
    _Pragma("unroll") for (int y = 0; y < 2; ++y) \
      acc[x][y] = MFMA16(af_[x], bf_[y], acc[x][y], 0, 0, 0); \
  } while (0)

#define P_SYNC3() \
  do { asm volatile("s_waitcnt vmcnt(3)" ::: "memory"); \
       __builtin_amdgcn_s_barrier(); } while (0)
#define P_SYNC0() \
  do { asm volatile("s_waitcnt vmcnt(0)" ::: "memory"); \
       __builtin_amdgcn_s_barrier(); } while (0)

#define P_ROT() do { cur_ = (cur_ == 2) ? 0 : cur_ + 1; \
                     nx2_ = (nx2_ == 2) ? 0 : nx2_ + 1; } while (0)

// KEXT >= 96, multiple of 32.
#define P_KLOOP(Arow, Brow, LDGA, LDGB, KEXT) \
  { P_STAGE(0, Arow, Brow, LDGA, LDGB, 0); \
    P_STAGE(1, Arow, Brow, LDGA, LDGB, 32); \
    P_SYNC3(); \
    int cur_ = 0, nx2_ = 2; \
    for (int k0 = 0; k0 < (KEXT); k0 += 32) { \
      const int kn_ = k0 + 64; \
      if (kn_ < (KEXT)) { \
        P_STAGE(nx2_, Arow, Brow, LDGA, LDGB, kn_); \
        P_COMPUTE(cur_); \
        P_SYNC3(); \
      } else if (k0 + 32 < (KEXT)) { \
        P_COMPUTE(cur_); \
        P_SYNC0(); \
      } else { \
        P_COMPUTE(cur_); \
      } \
      P_ROT(); \
    } }

// ====== CORE O (k_mfma_out): tile 128x128, BK=32, 3-buf, counted vmcnt ======
#define O_PROLOG \
  __shared__ __bf16 Al[3][128 * 32], Bl[3][128 * 32]; \
  int bx = blockIdx.x, by = blockIdx.y, bz = blockIdx.z; \
  xcd_remap(bx, by, bz); \
  const int b = bz, i0 = by * 128, n0 = bx * 128; \
  const int t = threadIdx.x, lane = t & 63, wave = t >> 6; \
  const int wm = wave >> 1, wn = wave & 1, quad = lane >> 4, col = lane & 15; \
  const int sr32 = wave * 32 + (lane >> 2); \
  const int swz = (((lane & 3) ^ ((lane >> 2) & 3) ^ ((lane >> 4) & 3)) * 8); \
  const int rdx = ((quad ^ (col & 3) ^ ((col >> 2) & 3)) * 8); \
  v4f acc[4][4]; \
  _Pragma("unroll") for (int x = 0; x < 4; ++x) \
  _Pragma("unroll") for (int y = 0; y < 4; ++y) \
  _Pragma("unroll") for (int r = 0; r < 4; ++r) acc[x][y][r] = 0.f;

#define O_STAGE(buf, Aptr, Bptr, LDGA, LDGB, k0) \
  do { \
    GLOAD16((Aptr) + (k0),                       &Al[buf][(wave * 32) * 32]); \
    GLOAD16((Aptr) + (size_t)16 * (LDGA) + (k0), &Al[buf][(wave * 32 + 16) * 32]); \
    GLOAD16((Bptr) + (k0),                       &Bl[buf][(wave * 32) * 32]); \
    GLOAD16((Bptr) + (size_t)16 * (LDGB) + (k0), &Bl[buf][(wave * 32 + 16) * 32]); \
  } while (0)

#define O_COMPUTE(buf) \
  do { \
    v8bf af_[4], bf_[4]; \
    _Pragma("unroll") for (int x = 0; x < 4; ++x) \
      af_[x] = *(const v8bf*)&Al[buf][(wm * 64 + x * 16 + col) * 32 + rdx]; \
    _Pragma("unroll") for (int y = 0; y < 4; ++y) \
      bf_[y] = *(const v8bf*)&Bl[buf][(wn * 64 + y * 16 + col) * 32 + rdx]; \
    _Pragma("unroll") for (int x = 0; x < 4; ++x) \
    _Pragma("unroll") for (int y = 0; y < 4; ++y) \
      acc[x][y] = MFMA16(af_[x], bf_[y], acc[x][y], 0, 0, 0); \
  } while (0)

#define O_SYNC4() \
  do { asm volatile("s_waitcnt vmcnt(4)" ::: "memory"); \
       __builtin_amdgcn_s_barrier(); } while (0)
#define O_SYNC0() \
  do { asm volatile("s_waitcnt vmcnt(0)" ::: "memory"); \
       __builtin_amdgcn_s_barrier(); } while (0)

#define O_ROT() do { cur_ = (cur_ == 2) ? 0 : cur_ + 1; \
                     nx2_ = (nx2_ == 2) ? 0 : nx2_ + 1; } while (0)

// -------- K1: cw1[b,i] = C.w1, qw2[b,j] = Q.w2; also emits Cbf = bf16(C)
// -------- and Qw3 = bf16(Q*w3) for the pure-bf16 k_mfma_S. ----
__global__ void k_rowdots(const float* __restrict__ C, const float* __restrict__ Q,
                          const float* __restrict__ w,
                          float* __restrict__ cw1, float* __restrict__ qw2,
                          __bf16* __restrict__ Cbf, __bf16* __restrict__ Qw3) {
  const int wid = threadIdx.x >> 6, lane = threadIdx.x & 63;
  const int row = blockIdx.x * 4 + wid;
  const bool isC = row < NB * LC;
  const int lr = isC ? row : row - NB * LC;
  const float* src = (isC ? C : Q) + (size_t)lr * DM;
  const float* wv  = isC ? w : (w + DM);
  const float* w3  = w + 2 * DM;
  __bf16* dst = (isC ? Cbf : Qw3) + (size_t)lr * DM;
  float v = 0.f;
#pragma unroll
  for (int s = 0; s < 2; ++s) {
    const int k = lane * 4 + s * 256;
    float4 f = *(const float4*)(src + k);
    float4 g = *(const float4*)(wv + k);
    v += f.x * g.x + f.y * g.y + f.z * g.z + f.w * g.w;
    v4bf h;
    if (isC) {
      h[0] = (__bf16)f.x; h[1] = (__bf16)f.y; h[2] = (__bf16)f.z; h[3] = (__bf16)f.w;
    } else {
      float4 s3 = *(const float4*)(w3 + k);
      h[0] = (__bf16)(f.x * s3.x); h[1] = (__bf16)(f.y * s3.y);
      h[2] = (__bf16)(f.z * s3.z); h[3] = (__bf16)(f.w * s3.w);
    }
    *(v4bf*)(dst + k) = h;
  }
#pragma unroll
  for (int off = 32; off; off >>= 1) v += __shfl_down(v, off, 64);
  if (lane == 0) {
    if (isC) cw1[row] = v;
    else     qw2[lr] = v;
  }
}

// ------- transpose cores: in[R][Cd] -> bf16 outT[Cd][R], one 64x64 tile ----
__device__ __forceinline__ void transpose_tile_f32(const float* __restrict__ in,
                                                   __bf16* __restrict__ outT,
                                                   int R, int Cd, int tbx, int tby, int tb) {
  __shared__ __bf16 tile[64][66];
  const int r0 = tby * 64, c0 = tbx * 64;
  const int tr = threadIdx.x >> 6, tc = threadIdx.x & 63;
  const float* inb = in + (size_t)tb * R * Cd;
  __bf16* outb = outT + (size_t)tb * Cd * R;
  for (int r = tr; r < 64; r += 4)
    tile[r][tc] = (__bf16)inb[(size_t)(r0 + r) * Cd + c0 + tc];
  __syncthreads();
  for (int c = tr; c < 64; c += 4)
    outb[(size_t)(c0 + c) * R + r0 + tc] = tile[tc][c];
}

__device__ __forceinline__ void transpose_tile_bf(const __bf16* __restrict__ in,
                                                  __bf16* __restrict__ outT,
                                                  int R, int Cd, int tbx, int tby, int tb) {
  __shared__ __bf16 tile[64][66];
  const int r0 = tby * 64, c0 = tbx * 64;
  const int tr = threadIdx.x >> 6, tc = threadIdx.x & 63;
  const __bf16* inb = in + (size_t)tb * R * Cd;
  __bf16* outb = outT + (size_t)tb * Cd * R;
  for (int r = tr; r < 64; r += 4)
    tile[r][tc] = inb[(size_t)(r0 + r) * Cd + c0 + tc];
  __syncthreads();
  for (int c = tr; c < 64; c += 4)
    outb[(size_t)(c0 + c) * R + r0 + tc] = tile[tc][c];
}

// ------- merged prep: transpose C (2048 blks, from Cbf when available) +
// ------- transpose Q (1024 blks) [+ OW cvt (1024 blks) in big-ws path] ----
__global__ void k_prep(const float* __restrict__ C, const __bf16* __restrict__ Cbf,
                       const float* __restrict__ Q, const float* __restrict__ OW,
                       __bf16* __restrict__ CT, __bf16* __restrict__ QT,
                       __bf16* __restrict__ OWb, int use_cbf) {
  const int id = blockIdx.x;
  if (id < 2048) {                      // C^T: (8, 16, 16)
    if (use_cbf) transpose_tile_bf(Cbf, CT, LC, DM, id & 7, (id >> 3) & 15, id >> 7);
    else         transpose_tile_f32(C,  CT, LC, DM, id & 7, (id >> 3) & 15, id >> 7);
  } else if (id < 3072) {               // Q^T: (8, 8, 16)
    const int id2 = id - 2048;
    transpose_tile_f32(Q, QT, LQ, DM, id2 & 7, (id2 >> 3) & 7, id2 >> 6);
  } else {                              // OW cvt: 1024 blocks x 1024 elems
    const size_t i = ((size_t)(id - 3072) * 256 + threadIdx.x) * 4;
    float4 f = *(const float4*)(OW + i);
    v4bf h; h[0] = (__bf16)f.x; h[1] = (__bf16)f.y; h[2] = (__bf16)f.z; h[3] = (__bf16)f.w;
    *(v4bf*)(OWb + i) = h;
  }
}

// ------- fallback late cvt: Cbf3 = bf16(C) and OWbf = bf16(out_w) -------
__global__ void k_cvt2b(const float* __restrict__ Cf, const float* __restrict__ OW,
                        __bf16* __restrict__ Cb3, __bf16* __restrict__ OWb) {
  const size_t NC = (size_t)NB * LC * DM;
  size_t i = ((size_t)blockIdx.x * 256 + threadIdx.x) * 4;
  if (i < NC) {
    float4 f = *(const float4*)(Cf + i);
    v4bf h; h[0] = (__bf16)f.x; h[1] = (__bf16)f.y; h[2] = (__bf16)f.z; h[3] = (__bf16)f.w;
    *(v4bf*)(Cb3 + i) = h;
  } else {
    size_t j = i - NC;
    float4 f = *(const float4*)(OW + j);
    v4bf h; h[0] = (__bf16)f.x; h[1] = (__bf16)f.y; h[2] = (__bf16)f.z; h[3] = (__bf16)f.w;
    *(v4bf*)(OWb + j) = h;
  }
}

// ---------------- G1: S = cw1 + qw2 + Cbf @ Qw3^T ----------------
__global__ __launch_bounds__(256) void k_mfma_S(
    const __bf16* __restrict__ Cbf, const __bf16* __restrict__ Qw3,
    const float* __restrict__ cw1, const float* __restrict__ qw2,
    float* __restrict__ S) {
  P_PROLOG
  const __bf16* Arow = Cbf + (size_t)b * LC * DM + (size_t)(i0 + srA) * DM + swz;
  const __bf16* Brow = Qw3 + (size_t)b * LQ * DM + (size_t)(n0 + srB) * DM + swz;
  P_KLOOP(Arow, Brow, DM, DM, DM)
  float* Sb = S + (size_t)b * LC * LQ;
#pragma unroll
  for (int x = 0; x < 4; ++x) {
    const int mB = i0 + wm * 64 + x * 16 + quad * 4;
    float cv[4];
#pragma unroll
    for (int r = 0; r < 4; ++r) cv[r] = cw1[b * LC + mB + r];
#pragma unroll
    for (int y = 0; y < 2; ++y) {
      const int j = n0 + wn * 32 + y * 16 + col;
      const float qv = qw2[b * LQ + j];
#pragma unroll
      for (int r = 0; r < 4; ++r)
        Sb[(size_t)(mB + r) * LQ + j] = acc[x][y][r] + cv[r] + qv;
    }
  }
}

// ---- fused: row softmax (qmask) -> S1  AND  per-64i-chunk column stats ----
__global__ __launch_bounds__(1024) void k_softstat(
    const float* __restrict__ S, const float* __restrict__ qmask,
    const float* __restrict__ cmask, __bf16* __restrict__ S1,
    float2* __restrict__ pstat) {
  __shared__ float2 cst[16][LQ];
  const int b = blockIdx.y, ic = blockIdx.x;
  const int tid = threadIdx.x, wv = tid >> 6, lane = tid & 63;
  const float* qm  = qmask + b * LQ;
  const float* cm  = cmask + b * LC + ic * 64;
  const float* Sb  = S  + ((size_t)b * LC + ic * 64) * LQ;
  __bf16*      S1b = S1 + ((size_t)b * LC + ic * 64) * LQ;
  float colm[8], cols[8];
#pragma unroll
  for (int tt = 0; tt < 8; ++tt) { colm[tt] = -3e38f; cols[tt] = 0.f; }
  for (int it = 0; it < 4; ++it) {
    const int r = wv * 4 + it;
    const float cmv = cm[r];
    const float* Srow = Sb + (size_t)r * LQ;
    float sv[8], l1[8];
    float m = -3e38f;
#pragma unroll
    for (int tt = 0; tt < 8; ++tt) {
      int j = lane + 64 * tt;
      sv[tt] = Srow[j];
      float qv = qm[j];
      l1[tt] = qv * sv[tt] + (1.f - qv) * NEGINF;
      m = fmaxf(m, l1[tt]);
    }
#pragma unroll
    for (int off = 32; off; off >>= 1) m = fmaxf(m, __shfl_xor(m, off, 64));
    float e[8], s = 0.f;
#pragma unroll
    for (int tt = 0; tt < 8; ++tt) { e[tt] = __expf(l1[tt] - m); s += e[tt]; }
#pragma unroll
    for (int off = 32; off; off >>= 1) s += __shfl_xor(s, off, 64);
    const float inv = 1.f / s;
#pragma unroll
    for (int tt = 0; tt < 8; ++tt)
      S1b[(size_t)r * LQ + lane + 64 * tt] = (__bf16)(e[tt] * inv);
    // column stats: cmv is 0/1 and wave-uniform -> skip masked rows entirely.
    if (cmv != 0.f) {
#pragma unroll
      for (int tt = 0; tt < 8; ++tt) {
        float l2 = sv[tt];
        if (l2 > colm[tt]) { cols[tt] *= __expf(colm[tt] - l2); colm[tt] = l2; }
        cols[tt] += __expf(l2 - colm[tt]);
      }
    }
  }
#pragma unroll
  for (int tt = 0; tt < 8; ++tt) cst[wv][lane + 64 * tt] = make_float2(colm[tt], cols[tt]);
  __syncthreads();
  if (tid < LQ) {
    float M = -3e38f, Sd = 0.f;
#pragma unroll
    for (int k = 0; k < 16; ++k) {
      float2 p = cst[k][tid];
      float nM = fmaxf(M, p.x);
      Sd = Sd * __expf(M - nM) + p.y * __expf(p.x - nM);
      M = nM;
    }
    pstat[((size_t)(b * 16 + ic) * LQ) + tid] = make_float2(M, Sd);
  }
}

// ---- col softmax phase 2: combine chunk stats, write TRANSPOSED S2T[j][i] ----
__global__ void k_colwrite(const float* __restrict__ S, const float* __restrict__ cmask,
                           const float2* __restrict__ pstat, __bf16* __restrict__ S2T) {
  __shared__ float Mf[64], If[64];
  __shared__ __bf16 tile[64][66];
  const int b = blockIdx.z, ic = blockIdx.y, j0 = blockIdx.x * 64;
  const int c = threadIdx.x & 63, ip = threadIdx.x >> 6;
  if (threadIdx.x < 64) {
    float M = -3e38f, Sd = 0.f;
#pragma unroll
    for (int k = 0; k < 16; ++k) {
      float2 p = pstat[((size_t)(b * 16 + k) * LQ) + j0 + threadIdx.x];
      float nM = fmaxf(M, p.x);
      Sd = Sd * __expf(M - nM) + p.y * __expf(p.x - nM);
      M = nM;
    }
    Mf[threadIdx.x] = M; If[threadIdx.x] = 1.f / Sd;
  }
  __syncthreads();
  const float M = Mf[c], inv = If[c];
  const float* Sb = S + ((size_t)b * LC + ic * 64) * LQ;
  const float* cm = cmask + b * LC + ic * 64;
  for (int r = ip; r < 64; r += 4) {
    if (cm[r] != 0.f)
      tile[r][c] = (__bf16)(__expf(Sb[(size_t)r * LQ + j0 + c] - M) * inv);
    else
      tile[r][c] = (__bf16)0.f;
  }
  __syncthreads();
  __bf16* S2Tb = S2T + ((size_t)b * LQ + j0) * LC + ic * 64;
  for (int jr = ip; jr < 64; jr += 4)
    S2Tb[(size_t)jr * LC + c] = tile[c][jr];
}

// ---------------- G2: A = S1 @ Q; epilogue also emits CA = bf16(C*A) ---------
__global__ __launch_bounds__(256) void k_mfma_A(
    const __bf16* __restrict__ S1, const __bf16* __restrict__ QT,
    const float* __restrict__ Cf, __bf16* __restrict__ Aw, __bf16* __restrict__ CAw) {
  P_PROLOG
  const __bf16* Arow = S1 + (size_t)b * LC * LQ + (size_t)(i0 + srA) * LQ + swz;
  const __bf16* Brow = QT + (size_t)b * DM * LQ + (size_t)(n0 + srB) * LQ + swz;
  P_KLOOP(Arow, Brow, LQ, LQ, LQ)
  const float* Cb = Cf + (size_t)b * LC * DM;
  __bf16* Ab  = Aw  + (size_t)b * LC * DM;
  __bf16* CAb = CAw + (size_t)b * LC * DM;
#pragma unroll
  for (int x = 0; x < 4; ++x) {
    const int mB = i0 + wm * 64 + x * 16 + quad * 4;
#pragma unroll
    for (int y = 0; y < 2; ++y) {
      const int n = n0 + wn * 32 + y * 16 + col;
#pragma unroll
      for (int r = 0; r < 4; ++r) {
        const float av = acc[x][y][r];
        const float cv = Cb[(size_t)(mB + r) * DM + n];
        Ab[(size_t)(mB + r) * DM + n]  = (__bf16)av;
        CAb[(size_t)(mB + r) * DM + n] = (__bf16)(av * cv);
      }
    }
  }
}

// ------- G3: S2TC^T[n][j]  (A=S2T rows, B=CT rows; K=Lc) ----
__global__ __launch_bounds__(256) void k_mfma_T(
    const __bf16* __restrict__ S2T, const __bf16* __restrict__ CT, __bf16* __restrict__ S2TCT) {
  P_PROLOG
  const int j0 = i0;
  const __bf16* Arow = S2T + (size_t)b * LQ * LC + (size_t)(j0 + srA) * LC + swz;
  const __bf16* Brow = CT  + (size_t)b * DM * LC + (size_t)(n0 + srB) * LC + swz;
  P_KLOOP(Arow, Brow, LC, LC, LC)
#pragma unroll
  for (int x = 0; x < 4; ++x) {
    const int jB = j0 + wm * 64 + x * 16 + quad * 4;
#pragma unroll
    for (int y = 0; y < 2; ++y) {
      const int n = n0 + wn * 32 + y * 16 + col;
      v4bf h;
#pragma unroll
      for (int r = 0; r < 4; ++r) h[r] = (__bf16)acc[x][y][r];
      *(v4bf*)&S2TCT[((size_t)b * DM + n) * LQ + jB] = h;
    }
  }
}

// ---------- G4: Bm = S1 @ S2TC; epilogue emits CB = bf16(C*Bm) only ----------
__global__ __launch_bounds__(256) void k_mfma_Bm(
    const __bf16* __restrict__ S1, const __bf16* __restrict__ S2TCT,
    const float* __restrict__ Cf, __bf16* __restrict__ CBw) {
  P_PROLOG
  const __bf16* Arow = S1    + (size_t)b * LC * LQ + (size_t)(i0 + srA) * LQ + swz;
  const __bf16* Brow = S2TCT + (size_t)b * DM * LQ + (size_t)(n0 + srB) * LQ + swz;
  P_KLOOP(Arow, Brow, LQ, LQ, LQ)
  const float* Cb = Cf + (size_t)b * LC * DM;
  __bf16* CBb = CBw + (size_t)b * LC * DM;
#pragma unroll
  for (int x = 0; x < 4; ++x) {
    const int mB = i0 + wm * 64 + x * 16 + quad * 4;
#pragma unroll
    for (int y = 0; y < 2; ++y) {
      const int n = n0 + wn * 32 + y * 16 + col;
#pragma unroll
      for (int r = 0; r < 4; ++r) {
        const float cv = Cb[(size_t)(mB + r) * DM + n];
        CBb[(size_t)(mB + r) * DM + n] = (__bf16)(acc[x][y][r] * cv);
      }
    }
  }
}

// -------- G5: out = [Cbf|Aw|CAw|CBw] @ OW^T + out_b  (pure 4-seg GEMM,
// -------- one continuous 64-step pipeline across segment boundaries) ------
__global__ __launch_bounds__(256) void k_mfma_out(
    const __bf16* __restrict__ Cb3, const __bf16* __restrict__ Aw,
    const __bf16* __restrict__ CAw, const __bf16* __restrict__ CBw,
    const __bf16* __restrict__ OWb, const float* __restrict__ ob,
    float* __restrict__ out) {
  O_PROLOG
  const size_t rowoff = (size_t)b * LC * DM + (size_t)(i0 + sr32) * DM + swz;
  const __bf16* Aseg[4] = {Cb3 + rowoff, Aw + rowoff, CAw + rowoff, CBw + rowoff};
  const __bf16* Brow0 = OWb + (size_t)(n0 + sr32) * D4 + swz;
  O_STAGE(0, Aseg[0], Brow0, DM, D4, 0);
  O_STAGE(1, Aseg[0], Brow0, DM, D4, 32);
  O_SYNC4();
  int cur_ = 0, nx2_ = 2;
#pragma unroll
  for (int seg = 0; seg < 4; ++seg) {
    const __bf16* Ac = Aseg[seg];
    const __bf16* An = Aseg[seg < 3 ? seg + 1 : 3];
    const __bf16* Bc = Brow0 + seg * DM;
    const __bf16* Bn = Brow0 + (seg < 3 ? seg + 1 : 3) * DM;
    for (int j = 0; j < 14; ++j) {          // steady: stage same-seg k+64
      O_STAGE(nx2_, Ac, Bc, DM, D4, (j + 2) * 32);
      O_COMPUTE(cur_);
      O_SYNC4();
      O_ROT();
    }
    if (seg < 3) {                          // boundary: stage next-seg k=0,32
      O_STAGE(nx2_, An, Bn, DM, D4, 0);
      O_COMPUTE(cur_);
      O_SYNC4();
      O_ROT();
      O_STAGE(nx2_, An, Bn, DM, D4, 32);
      O_COMPUTE(cur_);
      O_SYNC4();
      O_ROT();
    } else {                                // tail: steps 62, 63
      O_COMPUTE(cur_);
      O_SYNC0();
      O_ROT();
      O_COMPUTE(cur_);
    }
  }
  float* outb = out + (size_t)b * LC * DM;
#pragma unroll
  for (int x = 0; x < 4; ++x) {
    const int mB = i0 + wm * 64 + x * 16 + quad * 4;
#pragma unroll
    for (int y = 0; y < 4; ++y) {
      const int n = n0 + wn * 64 + y * 16 + col;
      const float bv = ob[n];
#pragma unroll
      for (int r = 0; r < 4; ++r)
        outb[(size_t)(mB + r) * DM + n] = acc[x][y][r] + bv;
    }
  }
}

extern "C" void kernel_launch(void* const* d_in, const int* in_sizes, int n_in,
                              void* d_out, int out_size, void* d_ws, size_t ws_size,
                              hipStream_t stream) {
  const float* C     = (const float*)d_in[0];
  const float* Q     = (const float*)d_in[1];
  const float* cmask = (const float*)d_in[2];
  const float* qmask = (const float*)d_in[3];
  const float* w     = (const float*)d_in[4];
  const float* out_w = (const float*)d_in[5];
  const float* out_b = (const float*)d_in[6];
  float* out = (float*)d_out;

  // ---- workspace carve: 128 KiB header + region R (R3 lifetime map).
  // Big-ws path (ws >= 90.125 MiB + header): Cbf persistent [72,88),
  // OWbf [88,90) -> k_cvt2b dropped; k_prep transposes C from Cbf (bf16 read).
  char* base = (char*)d_ws;
  float*  cw1   = (float*)base;
  float*  qw2   = (float*)(base + 65536);
  char*   R     = base + 131072;
  float*  S     = (float*)R;                          // [0,32)   steps 2-4
  __bf16* CT    = (__bf16*)R;                         // [0,16)   steps 5-6
  __bf16* Aw    = (__bf16*)R;                         // [0,16)   steps 8-11
  __bf16* QT    = (__bf16*)(R + (16u << 20));         // [16,24)  steps 7-8
  __bf16* CBw   = (__bf16*)(R + (16u << 20));         // [16,32)  steps 9-11
  __bf16* S1    = (__bf16*)(R + (32u << 20));         // [32,48)  steps 3-9
  __bf16* Qw3   = (__bf16*)(R + (48u << 20));         // [48,56)  steps 1-2
  __bf16* S2T   = (__bf16*)(R + (48u << 20));         // [48,64)  steps 4-6
  __bf16* CAw   = (__bf16*)(R + (48u << 20));         // [48,64)  steps 8-11
  float2* pstat = (float2*)(R + (64u << 20));         // [64,65)  steps 3-4
  __bf16* S2TCT = (__bf16*)(R + (64u << 20));         // [64,72)  steps 6-9
  (void)in_sizes; (void)n_in; (void)out_size;

  const size_t need_big = 131072 + (90ull << 20);
  const bool bigws = ws_size >= need_big;

  __bf16 *Cbf, *Cbf3, *OWbf;
  if (bigws) {
    Cbf  = (__bf16*)(R + (72u << 20));                // [72,88)  persistent
    Cbf3 = Cbf;
    OWbf = (__bf16*)(R + (88u << 20));                // [88,90)  persistent
  } else {
    Cbf  = (__bf16*)(R + (32u << 20));                // [32,48)  steps 1-2 (dies to S1)
    Cbf3 = (__bf16*)(R + (32u << 20));                // [32,48)  steps 10-11 (k_cvt2b)
    OWbf = (__bf16*)(R + (64u << 20));                // [64,66)  steps 10-11 (k_cvt2b)
  }

  // 1
  k_rowdots<<<(NB * LC + NB * LQ) / 4, 256, 0, stream>>>(C, Q, w, cw1, qw2, Cbf, Qw3);
  // 2
  k_mfma_S<<<dim3(LQ / 64, LC / 128, NB), 256, 0, stream>>>(Cbf, Qw3, cw1, qw2, S);
  // 3
  k_softstat<<<dim3(LC / 64, NB), 1024, 0, stream>>>(S, qmask, cmask, S1, pstat);
  // 4
  k_colwrite<<<dim3(LQ / 64, LC / 64, NB), 256, 0, stream>>>(S, cmask, pstat, S2T);
  // 5: merged transposes (+ OW cvt in big path)
  k_prep<<<bigws ? 4096 : 3072, 256, 0, stream>>>(C, Cbf, Q, out_w, CT, QT, OWbf,
                                                  bigws ? 1 : 0);
  // 6
  k_mfma_T<<<dim3(DM / 64, LQ / 128, NB), 256, 0, stream>>>(S2T, CT, S2TCT);
  // 7
  k_mfma_A<<<dim3(DM / 64, LC / 128, NB), 256, 0, stream>>>(S1, QT, C, Aw, CAw);
  // 8
  k_mfma_Bm<<<dim3(DM / 64, LC / 128, NB), 256, 0, stream>>>(S1, S2TCT, C, CBw);
  // 9 (fallback only): Cbf3 = bf16(C), OWbf = bf16(out_w)
  if (!bigws)
    k_cvt2b<<<(NB * LC * DM + DM * D4) / 1024, 256, 0, stream>>>(C, out_w, Cbf3, OWbf);
  // 10
  k_mfma_out<<<dim3(DM / 128, LC / 128, NB), 256, 0, stream>>>(Cbf3, Aw, CAw, CBw, OWbf, out_b, out);
}